// Round 2
// 5059.524 us; speedup vs baseline: 1.0197x; 1.0197x over previous
//
#include <hip/hip_runtime.h>
#include <math.h>

#define NEGV -1e9f
#define SK_TAU 0.05f

typedef __attribute__((ext_vector_type(4))) float f32x4;
typedef __attribute__((ext_vector_type(8))) short short8;

#define GLDS(g, l) __builtin_amdgcn_global_load_lds( \
    (const __attribute__((address_space(1))) void*)(g), \
    (__attribute__((address_space(3))) void*)(l), 16, 0, 0)

// ---------------- bf16 split helpers ----------------
__device__ inline unsigned bf16rtn(float x) {
    unsigned u = __float_as_uint(x);
    return (u + 0x7FFFu + ((u >> 16) & 1u)) >> 16;
}
__device__ inline float bf2f(short h) {
    return __uint_as_float(((unsigned)(unsigned short)h) << 16);
}
__device__ inline void split1(float x, short& h, short& l) {
    unsigned hu = bf16rtn(x);
    h = (short)hu;
    float r = x - __uint_as_float(hu << 16);
    l = (short)(__float_as_uint(r) >> 16);
}
__device__ inline void cvt4(const float4 v, short4& h, short4& l) {
    unsigned h0 = bf16rtn(v.x), h1 = bf16rtn(v.y), h2 = bf16rtn(v.z), h3 = bf16rtn(v.w);
    h.x = (short)h0; h.y = (short)h1; h.z = (short)h2; h.w = (short)h3;
    float l0 = v.x - __uint_as_float(h0 << 16);
    float l1 = v.y - __uint_as_float(h1 << 16);
    float l2 = v.z - __uint_as_float(h2 << 16);
    float l3 = v.w - __uint_as_float(h3 << 16);
    l.x = (short)(__float_as_uint(l0) >> 16);
    l.y = (short)(__float_as_uint(l1) >> 16);
    l.z = (short)(__float_as_uint(l2) >> 16);
    l.w = (short)(__float_as_uint(l3) >> 16);
}

// ---------------- inv column L1 norm ----------------
__global__ __launch_bounds__(256) void colnorm_k(const float* __restrict__ A,
                                                 float* __restrict__ inv)
{
    int idx = blockIdx.x * 256 + threadIdx.x;
    int b = idx >> 8, m = idx & 255;
    const float* p = A + (long long)b * 65536 + m;
    float s = 0.f;
    #pragma unroll 8
    for (int n = 0; n < 256; ++n) s += fabsf(p[n * 256]);
    inv[idx] = 1.f / fmaxf(s, 1e-12f);
}

// ---------------- fp32 -> split planes ----------------
__global__ __launch_bounds__(256) void split_mat(const float* __restrict__ X,
                                                 short* __restrict__ H,
                                                 short* __restrict__ L, long long n4)
{
    long long i = (long long)blockIdx.x * 256 + threadIdx.x;
    long long stride = (long long)gridDim.x * 256;
    for (; i < n4; i += stride) {
        float4 v = ((const float4*)X)[i];
        short4 h, l;
        cvt4(v, h, l);
        ((short4*)H)[i] = h;
        ((short4*)L)[i] = l;
    }
}

// ---------------- weight slice -> transposed split planes ----------------
__global__ __launch_bounds__(256) void wsplit_t(const float* __restrict__ W, int ldw, int c0,
                                                short* __restrict__ H, short* __restrict__ L,
                                                int K)
{
    __shared__ float tile[32][33];
    int kt = blockIdx.x * 32, ct = blockIdx.y * 32;
    int tx = threadIdx.x & 31, ty = threadIdx.x >> 5;
    #pragma unroll
    for (int i = 0; i < 4; ++i)
        tile[ty + 8 * i][tx] = W[(long long)(kt + ty + 8 * i) * ldw + c0 + ct + tx];
    __syncthreads();
    #pragma unroll
    for (int i = 0; i < 4; ++i) {
        int nn = ty + 8 * i, kk = tx;
        float v = tile[kk][nn];
        short h, l;
        split1(v, h, l);
        long long o = (long long)(ct + nn) * K + kt + kk;
        H[o] = h; L[o] = l;
    }
}

// =====================================================================
// DMA split-bf16 MFMA GEMM, depth-2 double-buffered.
// C = epi( A[M,K] @ B^T ); A:[M][K] planes, B:[N][K] planes.
// Per panel: barrier (drains DMA of current panel, issued last iter);
// issue DMA for next panel into the other buffer; ds_read + 48 MFMA.
// Chunked LDS: tile = 8 chunks of (16 rows x 32 k); frag read = linear b128.
// OM: 0 = fp32 store, 1 = split store, 2 = split accumulate.
// =====================================================================
template <int OM>
__global__ __launch_bounds__(256, 2) void gemm_dma(
    const short* __restrict__ Ah_, const short* __restrict__ Al_,
    const short* __restrict__ Bh_, const short* __restrict__ Bl_,
    int K,
    float* __restrict__ Cf, short* __restrict__ Ch, short* __restrict__ Cl, int ldC,
    const float* __restrict__ bias, int relu)
{
    __shared__ short lds[2][16384];   // [buf][Ah|Al|Bh|Bl x 4096], 32 KB each

    const int tid = threadIdx.x;
    const int wave = tid >> 6, L = tid & 63;
    const int m0 = blockIdx.y * 128, n0 = blockIdx.x * 128;
    const int wm = (wave & 1) * 64, wn = (wave >> 1) * 64;

    const int lm = L & 15;
    const int lh = (L >> 4) * 8;
    const int c0 = wave * 2;

    long long ga[2], gb[2];
    #pragma unroll
    for (int c = 0; c < 2; ++c) {
        ga[c] = (long long)(m0 + (c0 + c) * 16 + lm) * K + lh;
        gb[c] = (long long)(n0 + (c0 + c) * 16 + lm) * K + lh;
    }

    f32x4 acc[4][4];
    #pragma unroll
    for (int i = 0; i < 4; ++i)
        #pragma unroll
        for (int j = 0; j < 4; ++j)
            acc[i][j] = (f32x4){0.f, 0.f, 0.f, 0.f};

    // prologue: panel 0 -> buf 0
    #pragma unroll
    for (int c = 0; c < 2; ++c) {
        const int sl = (c0 + c) * 512;
        GLDS(Ah_ + ga[c], lds[0] + sl);
        GLDS(Al_ + ga[c], lds[0] + 4096 + sl);
        GLDS(Bh_ + gb[c], lds[0] + 8192 + sl);
        GLDS(Bl_ + gb[c], lds[0] + 12288 + sl);
    }

    int cur = 0;
    for (int k0 = 0; k0 < K; k0 += 32) {
        __syncthreads();   // drains vmcnt: DMA into lds[cur] complete; prev reads of lds[1-cur] done

        if (k0 + 32 < K) {
            short* nb = lds[1 - cur];
            #pragma unroll
            for (int c = 0; c < 2; ++c) {
                const int sl = (c0 + c) * 512;
                GLDS(Ah_ + ga[c] + k0 + 32, nb + sl);
                GLDS(Al_ + ga[c] + k0 + 32, nb + 4096 + sl);
                GLDS(Bh_ + gb[c] + k0 + 32, nb + 8192 + sl);
                GLDS(Bl_ + gb[c] + k0 + 32, nb + 12288 + sl);
            }
        }

        const short* AhS = lds[cur];
        const short* AlS = lds[cur] + 4096;
        const short* BhS = lds[cur] + 8192;
        const short* BlS = lds[cur] + 12288;

        short8 AF[4], ALF[4], BF[4], BLF[4];
        const int ab = (wm >> 4) * 512 + L * 8;
        const int bb = (wn >> 4) * 512 + L * 8;
        #pragma unroll
        for (int t = 0; t < 4; ++t) {
            AF[t]  = *(const short8*)(AhS + ab + t * 512);
            ALF[t] = *(const short8*)(AlS + ab + t * 512);
            BF[t]  = *(const short8*)(BhS + bb + t * 512);
            BLF[t] = *(const short8*)(BlS + bb + t * 512);
        }
        #pragma unroll
        for (int ti = 0; ti < 4; ++ti)
            #pragma unroll
            for (int tj = 0; tj < 4; ++tj) {
                acc[ti][tj] = __builtin_amdgcn_mfma_f32_16x16x32_bf16(AF[ti],  BF[tj],  acc[ti][tj], 0, 0, 0);
                acc[ti][tj] = __builtin_amdgcn_mfma_f32_16x16x32_bf16(AF[ti],  BLF[tj], acc[ti][tj], 0, 0, 0);
                acc[ti][tj] = __builtin_amdgcn_mfma_f32_16x16x32_bf16(ALF[ti], BF[tj],  acc[ti][tj], 0, 0, 0);
            }
        cur ^= 1;
    }

    // ---- epilogue: C/D layout col = lane&15, row = (lane>>4)*4 + reg ----
    const int lcol = L & 15, lrow = (L >> 4) * 4;
    float bv[4];
    #pragma unroll
    for (int tj = 0; tj < 4; ++tj)
        bv[tj] = bias ? bias[n0 + wn + tj * 16 + lcol] : 0.f;

    #pragma unroll
    for (int ti = 0; ti < 4; ++ti) {
        #pragma unroll
        for (int r = 0; r < 4; ++r) {
            int grow = m0 + wm + ti * 16 + lrow + r;
            #pragma unroll
            for (int tj = 0; tj < 4; ++tj) {
                int gcol = n0 + wn + tj * 16 + lcol;
                float v = acc[ti][tj][r] + bv[tj];
                if (relu) v = fmaxf(v, 0.f);
                long long idx = (long long)grow * ldC + gcol;
                if (OM == 0) {
                    Cf[idx] = v;
                } else {
                    if (OM == 2) v += bf2f(Ch[idx]) + bf2f(Cl[idx]);
                    short hh, ll;
                    split1(v, hh, ll);
                    Ch[idx] = hh;
                    Cl[idx] = ll;
                }
            }
        }
    }
}

// =====================================================================
// Hybrid GEMM for the fused cross-graph update:
//   C = [A1 | A2] @ Bf + bias, split-bf16 store.
// A1,A2: pre-split [8192][2048] planes (K switches source at K1).
// Bf: fp32 [K][2048] weight (Wc), converted in-kernel.
// Structure = gemm_dma: single barrier per 32-K panel, A-planes via
// global_load_lds DMA (chunked layout), B reg-staged 2 panels ahead into
// the same chunked layout (named reg sets brA/brB, statically indexed),
// depth-2 LDS double buffer.
// =====================================================================
__global__ __launch_bounds__(256, 2) void gemm_hyb(
    const short* __restrict__ A1h, const short* __restrict__ A1l,
    const short* __restrict__ A2h, const short* __restrict__ A2l,
    const float* __restrict__ Bf, int K1, int K,
    short* __restrict__ Ch, short* __restrict__ Cl, int ldC,
    const float* __restrict__ bias)
{
    __shared__ short lds[2][16384];   // [buf][Ah|Al|Bh|Bl x 4096]

    const int tid = threadIdx.x;
    const int wave = tid >> 6, L = tid & 63;
    const int m0 = blockIdx.y * 128, n0 = blockIdx.x * 128;
    const int wm = (wave & 1) * 64, wn = (wave >> 1) * 64;
    const int lm = L & 15, lh = (L >> 4) * 8;
    const int c0 = wave * 2;

    // A sources are both [.][2048] row-major
    long long grow[2];
    #pragma unroll
    for (int c = 0; c < 2; ++c)
        grow[c] = (long long)(m0 + (c0 + c) * 16 + lm) * 2048 + lh;

    // B mapping: thread owns col bn, k-offsets {bkb + g*8 + i}
    const int bn = tid & 127, bkb = (tid >> 7) * 4;
    const float* bp = Bf + (long long)bkb * 2048 + n0 + bn;
    const int bws = (bn >> 4) * 512 + (bn & 15) * 8 + bkb;

    f32x4 acc[4][4];
    #pragma unroll
    for (int i = 0; i < 4; ++i)
        #pragma unroll
        for (int j = 0; j < 4; ++j)
            acc[i][j] = (f32x4){0.f, 0.f, 0.f, 0.f};

    auto STAGE = [&](short* buf, int k0) {
        const short *sh, *sl;
        int ko;
        if (k0 < K1) { sh = A1h; sl = A1l; ko = k0; }
        else         { sh = A2h; sl = A2l; ko = k0 - K1; }
        #pragma unroll
        for (int c = 0; c < 2; ++c) {
            const int so = (c0 + c) * 512;
            GLDS(sh + grow[c] + ko, buf + so);
            GLDS(sl + grow[c] + ko, buf + 4096 + so);
        }
    };
    auto LOADB = [&](float br[16], int k0) {
        #pragma unroll
        for (int g = 0; g < 4; ++g)
            #pragma unroll
            for (int i = 0; i < 4; ++i)
                br[g * 4 + i] = bp[((long long)k0 + g * 8 + i) * 2048];
    };
    auto WRITEB = [&](short* buf, const float br[16]) {
        #pragma unroll
        for (int g = 0; g < 4; ++g) {
            float4 v = {br[g * 4 + 0], br[g * 4 + 1], br[g * 4 + 2], br[g * 4 + 3]};
            short4 h4, l4;
            cvt4(v, h4, l4);
            *(short4*)(buf + 8192  + bws + g * 128) = h4;
            *(short4*)(buf + 12288 + bws + g * 128) = l4;
        }
    };

    const int ab = (wm >> 4) * 512 + L * 8;
    const int bb = (wn >> 4) * 512 + L * 8;
    auto COMPUTE = [&](const short* buf) {
        const short* AhS = buf;
        const short* AlS = buf + 4096;
        const short* BhS = buf + 8192;
        const short* BlS = buf + 12288;
        short8 AF[4], ALF[4], BFr[4], BLF[4];
        #pragma unroll
        for (int t = 0; t < 4; ++t) {
            AF[t]  = *(const short8*)(AhS + ab + t * 512);
            ALF[t] = *(const short8*)(AlS + ab + t * 512);
            BFr[t] = *(const short8*)(BhS + bb + t * 512);
            BLF[t] = *(const short8*)(BlS + bb + t * 512);
        }
        #pragma unroll
        for (int ti = 0; ti < 4; ++ti)
            #pragma unroll
            for (int tj = 0; tj < 4; ++tj) {
                acc[ti][tj] = __builtin_amdgcn_mfma_f32_16x16x32_bf16(AF[ti],  BFr[tj], acc[ti][tj], 0, 0, 0);
                acc[ti][tj] = __builtin_amdgcn_mfma_f32_16x16x32_bf16(AF[ti],  BLF[tj], acc[ti][tj], 0, 0, 0);
                acc[ti][tj] = __builtin_amdgcn_mfma_f32_16x16x32_bf16(ALF[ti], BFr[tj], acc[ti][tj], 0, 0, 0);
            }
    };

    const int NT = K >> 5;          // panels; K=4096 -> 128 (even, >=4)
    float brA[16], brB[16];

    // prologue: panel0 -> buf0 (A DMA + B regs->LDS); panels 1,2 -> regs
    LOADB(brA, 0);
    STAGE(lds[0], 0);
    LOADB(brB, 32);
    WRITEB(lds[0], brA);
    LOADB(brA, 64);

    for (int t = 0; t < NT; t += 2) {
        // even body: consume buf0 (panel t), fill buf1 (panel t+1)
        __syncthreads();
        {
            STAGE(lds[1], (t + 1) << 5);        // t+1 <= NT-1 always (NT even)
            WRITEB(lds[1], brB);
        }
        if (t + 3 < NT) LOADB(brB, (t + 3) << 5);
        COMPUTE(lds[0]);

        // odd body: consume buf1 (panel t+1), fill buf0 (panel t+2)
        __syncthreads();
        if (t + 2 < NT) {
            STAGE(lds[0], (t + 2) << 5);
            WRITEB(lds[0], brA);
        }
        if (t + 4 < NT) LOADB(brA, (t + 4) << 5);
        COMPUTE(lds[1]);
    }

    // ---- epilogue: split store + bias ----
    const int lcol = L & 15, lrow = (L >> 4) * 4;
    float bv[4];
    #pragma unroll
    for (int tj = 0; tj < 4; ++tj)
        bv[tj] = bias ? bias[n0 + wn + tj * 16 + lcol] : 0.f;

    #pragma unroll
    for (int ti = 0; ti < 4; ++ti) {
        #pragma unroll
        for (int r = 0; r < 4; ++r) {
            int gr = m0 + wm + ti * 16 + lrow + r;
            #pragma unroll
            for (int tj = 0; tj < 4; ++tj) {
                int gcol = n0 + wn + tj * 16 + lcol;
                float v = acc[ti][tj][r] + bv[tj];
                long long idx = (long long)gr * ldC + gcol;
                short hh, ll;
                split1(v, hh, ll);
                Ch[idx] = hh;
                Cl[idx] = ll;
            }
        }
    }
}

// ---------------- batched fp32 VALU GEMM (256x2048x256 per batch) ----------------
template <bool TA, bool ACC>
__global__ __launch_bounds__(256, 2) void bgemm(
    const float* __restrict__ A,
    const short* __restrict__ Bh_, const short* __restrict__ Bl_,
    short* __restrict__ Ch, short* __restrict__ Cl,
    const float* __restrict__ colscale)
{
    __shared__ float As[16][132];
    __shared__ float Bs[16][132];

    const int N = 2048;
    const long long sB = 524288;
    int z = blockIdx.z;
    const float* Az = A + (long long)z * 65536;
    const float* cs = colscale ? colscale + z * 256 : nullptr;

    int n0 = blockIdx.x * 128, m0 = blockIdx.y * 128;
    int tid = threadIdx.x;
    int tx = tid & 15, ty = tid >> 4;

    float accv[8][8];
    #pragma unroll
    for (int i = 0; i < 8; ++i)
        #pragma unroll
        for (int j = 0; j < 8; ++j) accv[i][j] = 0.f;

    for (int k0 = 0; k0 < 256; k0 += 16) {
        if (!TA) {
            #pragma unroll
            for (int i = 0; i < 2; ++i) {
                int lin = tid + i * 256;
                int r  = lin >> 2;
                int c4 = (lin & 3) * 4;
                float4 v = *(const float4*)(Az + (long long)(m0 + r) * 256 + k0 + c4);
                if (cs) {
                    v.x *= cs[k0 + c4 + 0]; v.y *= cs[k0 + c4 + 1];
                    v.z *= cs[k0 + c4 + 2]; v.w *= cs[k0 + c4 + 3];
                }
                As[c4 + 0][r] = v.x; As[c4 + 1][r] = v.y;
                As[c4 + 2][r] = v.z; As[c4 + 3][r] = v.w;
            }
        } else {
            #pragma unroll
            for (int i = 0; i < 2; ++i) {
                int lin = tid + i * 256;
                int kk = lin >> 5;
                int m4 = (lin & 31) * 4;
                *(float4*)&As[kk][m4] =
                    *(const float4*)(Az + (long long)(k0 + kk) * 256 + m0 + m4);
            }
        }
        #pragma unroll
        for (int i = 0; i < 2; ++i) {
            int lin = tid + i * 256;
            int kk = lin >> 5;
            int n4 = (lin & 31) * 4;
            long long off = (long long)z * sB + (long long)(k0 + kk) * N + n0 + n4;
            short4 h = *(const short4*)(Bh_ + off);
            short4 l = *(const short4*)(Bl_ + off);
            Bs[kk][n4 + 0] = bf2f(h.x) + bf2f(l.x);
            Bs[kk][n4 + 1] = bf2f(h.y) + bf2f(l.y);
            Bs[kk][n4 + 2] = bf2f(h.z) + bf2f(l.z);
            Bs[kk][n4 + 3] = bf2f(h.w) + bf2f(l.w);
        }
        __syncthreads();

        #pragma unroll
        for (int kk = 0; kk < 16; ++kk) {
            float a[8], b[8];
            *(float4*)&a[0] = *(const float4*)&As[kk][ty * 8];
            *(float4*)&a[4] = *(const float4*)&As[kk][ty * 8 + 4];
            *(float4*)&b[0] = *(const float4*)&Bs[kk][tx * 8];
            *(float4*)&b[4] = *(const float4*)&Bs[kk][tx * 8 + 4];
            #pragma unroll
            for (int i = 0; i < 8; ++i)
                #pragma unroll
                for (int j = 0; j < 8; ++j)
                    accv[i][j] = fmaf(a[i], b[j], accv[i][j]);
        }
        __syncthreads();
    }

    #pragma unroll
    for (int i = 0; i < 8; ++i) {
        int rowl = m0 + ty * 8 + i;
        long long base = (long long)z * sB + (long long)rowl * N;
        #pragma unroll
        for (int j = 0; j < 8; ++j) {
            int col = n0 + tx * 8 + j;
            long long idx = base + col;
            float v = accv[i][j];
            if (ACC) v += bf2f(Ch[idx]) + bf2f(Cl[idx]);
            short hh, ll;
            split1(v, hh, ll);
            Ch[idx] = hh;
            Cl[idx] = ll;
        }
    }
}

// ---------------- fp64-accumulate affinity GEMM ----------------
__global__ __launch_bounds__(256) void gemm_bt_f64(
    const float* __restrict__ A,
    const short* __restrict__ Bh_, const short* __restrict__ Bl_,
    float* __restrict__ C)
{
    __shared__ float As[16][65];
    __shared__ float Bs[16][65];

    const int K = 2048;
    int z = blockIdx.z;
    const float* Az = A + (long long)z * 524288;
    C += (long long)z * 65536;

    int n0 = blockIdx.x * 64;
    int m0 = blockIdx.y * 64;
    int tid = threadIdx.x;
    int tx = tid & 15;
    int ty = tid >> 4;

    double acc[4][4];
    #pragma unroll
    for (int i = 0; i < 4; ++i)
        #pragma unroll
        for (int j = 0; j < 4; ++j) acc[i][j] = 0.0;

    int r  = tid >> 2;
    int c4 = (tid & 3) * 4;

    for (int k0 = 0; k0 < K; k0 += 16) {
        {
            const float4 v = *(const float4*)(Az + (long long)(m0 + r) * K + k0 + c4);
            As[c4 + 0][r] = v.x; As[c4 + 1][r] = v.y;
            As[c4 + 2][r] = v.z; As[c4 + 3][r] = v.w;
        }
        {
            long long off = (long long)z * 524288 + (long long)(n0 + r) * K + k0 + c4;
            short4 h = *(const short4*)(Bh_ + off);
            short4 l = *(const short4*)(Bl_ + off);
            Bs[c4 + 0][r] = bf2f(h.x) + bf2f(l.x);
            Bs[c4 + 1][r] = bf2f(h.y) + bf2f(l.y);
            Bs[c4 + 2][r] = bf2f(h.z) + bf2f(l.z);
            Bs[c4 + 3][r] = bf2f(h.w) + bf2f(l.w);
        }
        __syncthreads();

        #pragma unroll
        for (int kk = 0; kk < 16; ++kk) {
            double a[4], b[4];
            #pragma unroll
            for (int i = 0; i < 4; ++i) a[i] = (double)As[kk][ty + 16 * i];
            #pragma unroll
            for (int j = 0; j < 4; ++j) b[j] = (double)Bs[kk][tx + 16 * j];
            #pragma unroll
            for (int i = 0; i < 4; ++i)
                #pragma unroll
                for (int j = 0; j < 4; ++j)
                    acc[i][j] = fma(a[i], b[j], acc[i][j]);
        }
        __syncthreads();
    }

    #pragma unroll
    for (int i = 0; i < 4; ++i) {
        int rowl = m0 + ty + 16 * i;
        #pragma unroll
        for (int j = 0; j < 4; ++j)
            C[(long long)rowl * 256 + n0 + tx + 16 * j] = (float)acc[i][j];
    }
}

// =====================================================================
// Fused Sinkhorn: one 1024-thread block per batch; S register-resident.
// =====================================================================
__global__ __launch_bounds__(1024, 4) void sk_fused(float* __restrict__ S,
                                                    const int* __restrict__ n1)
{
    __shared__ float pmax[16][256];
    __shared__ float psum[16][256];
    __shared__ float lseS[256];

    const int b = blockIdx.x;
    const int tid = threadIdx.x;
    const int w = tid >> 6, l = tid & 63;
    const int lim = n1[b];
    float* Sb = S + (long long)b * 65536;

    float4 v[16];
    #pragma unroll
    for (int r = 0; r < 16; ++r) {
        int n = w * 16 + r;
        if (n < lim) {
            float4 x = *(const float4*)(Sb + n * 256 + l * 4);
            v[r].x = x.x / SK_TAU; v[r].y = x.y / SK_TAU;
            v[r].z = x.z / SK_TAU; v[r].w = x.w / SK_TAU;
        } else {
            v[r] = (float4){NEGV, NEGV, NEGV, NEGV};
        }
    }

    for (int it = 0; it < 10; ++it) {
        if ((it & 1) == 0) {
            #pragma unroll
            for (int r = 0; r < 16; ++r) {
                if (w * 16 + r >= lim) continue;
                float m = fmaxf(fmaxf(v[r].x, v[r].y), fmaxf(v[r].z, v[r].w));
                #pragma unroll
                for (int off = 1; off < 64; off <<= 1) m = fmaxf(m, __shfl_xor(m, off));
                float s = expf(v[r].x - m) + expf(v[r].y - m) +
                          expf(v[r].z - m) + expf(v[r].w - m);
                #pragma unroll
                for (int off = 1; off < 64; off <<= 1) s += __shfl_xor(s, off);
                float lse = m + logf(s);
                v[r].x -= lse; v[r].y -= lse; v[r].z -= lse; v[r].w -= lse;
            }
        } else {
            float cm[4] = {-3.4e38f, -3.4e38f, -3.4e38f, -3.4e38f};
            #pragma unroll
            for (int r = 0; r < 16; ++r) {
                cm[0] = fmaxf(cm[0], v[r].x); cm[1] = fmaxf(cm[1], v[r].y);
                cm[2] = fmaxf(cm[2], v[r].z); cm[3] = fmaxf(cm[3], v[r].w);
            }
            float cs[4] = {0.f, 0.f, 0.f, 0.f};
            #pragma unroll
            for (int r = 0; r < 16; ++r) {
                cs[0] += expf(v[r].x - cm[0]); cs[1] += expf(v[r].y - cm[1]);
                cs[2] += expf(v[r].z - cm[2]); cs[3] += expf(v[r].w - cm[3]);
            }
            #pragma unroll
            for (int j = 0; j < 4; ++j) {
                pmax[w][l * 4 + j] = cm[j];
                psum[w][l * 4 + j] = cs[j];
            }
            __syncthreads();
            if (tid < 256) {
                float m = -3.4e38f, s = 0.f;
                #pragma unroll
                for (int ww = 0; ww < 16; ++ww) {
                    float pm = pmax[ww][tid], ps = psum[ww][tid];
                    float nm = fmaxf(m, pm);
                    s = s * expf(m - nm) + ps * expf(pm - nm);
                    m = nm;
                }
                lseS[tid] = m + logf(s);
            }
            __syncthreads();
            float l0 = lseS[l * 4 + 0], l1 = lseS[l * 4 + 1];
            float l2 = lseS[l * 4 + 2], l3 = lseS[l * 4 + 3];
            #pragma unroll
            for (int r = 0; r < 16; ++r) {
                if (w * 16 + r >= lim) continue;
                v[r].x -= l0; v[r].y -= l1; v[r].z -= l2; v[r].w -= l3;
            }
        }
    }

    #pragma unroll
    for (int r = 0; r < 16; ++r) {
        int n = w * 16 + r;
        float4 o;
        if (n < lim) {
            o.x = expf(v[r].x); o.y = expf(v[r].y);
            o.z = expf(v[r].z); o.w = expf(v[r].w);
        } else {
            o = (float4){0.f, 0.f, 0.f, 0.f};
        }
        *(float4*)(Sb + n * 256 + l * 4) = o;
    }
}

// ---------------- launch wrappers ----------------
static void gsp(hipStream_t st, int om, const short* Ah, const short* Al,
                const short* Bh, const short* Bl, int Ns, int K,
                float* Cf, short* Ch, short* Cl, const float* bias, int relu)
{
    dim3 grid(Ns / 128, 64), block(256);
    if (om == 0)
        gemm_dma<0><<<grid, block, 0, st>>>(Ah, Al, Bh, Bl, K, Cf, nullptr, nullptr, 2048, bias, relu);
    else if (om == 1)
        gemm_dma<1><<<grid, block, 0, st>>>(Ah, Al, Bh, Bl, K, nullptr, Ch, Cl, 2048, bias, relu);
    else
        gemm_dma<2><<<grid, block, 0, st>>>(Ah, Al, Bh, Bl, K, nullptr, Ch, Cl, 2048, bias, relu);
}

static void wsp(hipStream_t st, const float* W, int Krows, int c0, int ncols,
                short* H, short* L)
{
    dim3 grid(Krows / 32, ncols / 32);
    wsplit_t<<<grid, 256, 0, st>>>(W, 2048, c0, H, L, Krows);
}

// ---------------- driver ----------------
extern "C" void kernel_launch(void* const* d_in, const int* in_sizes, int n_in,
                              void* d_out, int out_size, void* d_ws, size_t ws_size,
                              hipStream_t stream)
{
    const float* feat1 = (const float*)d_in[0];
    const float* feat2 = (const float*)d_in[1];
    const float* A1    = (const float*)d_in[2];
    const float* A2    = (const float*)d_in[3];
    const int*   n1    = (const int*)d_in[4];
    const float* W0a = (const float*)d_in[8];  const float* b0a = (const float*)d_in[9];
    const float* W0u = (const float*)d_in[10]; const float* b0u = (const float*)d_in[11];
    const float* W1a = (const float*)d_in[12]; const float* b1a = (const float*)d_in[13];
    const float* W1u = (const float*)d_in[14]; const float* b1u = (const float*)d_in[15];
    const float* Wc  = (const float*)d_in[16]; const float* bc  = (const float*)d_in[17];
    const float* Aaff0 = (const float*)d_in[18];
    const float* Aaff1 = (const float*)d_in[19];

    const long long TSZ = 16777216LL;
    const long long PL  = 16777216LL;
    const long long PF  = 8388608LL;

    float* T1f = (float*)d_ws;
    float* T2f = T1f + TSZ;
    float* T3f = T2f + TSZ;
    float* T4f = T3f + TSZ;
    short *T1h = (short*)T1f, *T1l = T1h + PL;
    short *T2h = (short*)T2f, *T2l = T2h + PL;
    short *T3h = (short*)T3f, *T3l = T3h + PL;
    short *T4h = (short*)T4f, *T4l = T4h + PL;

    short* f1h = (short*)T4f;      short* f1l = f1h + PF;
    short* f2h = f1h + 2 * PF;     short* f2l = f1h + 3 * PF;
    float* invA = (float*)T4f;
    float* invB = invA + 8192;

    float* S   = (float*)d_out;
    short* swh = (short*)d_out;
    short* swl = swh + 2097152;
    float* inv1 = S;
    float* inv2 = S + 8192;

    dim3 bgrid(16, 2, 32), bblk(256);

    // ===== Phase 0: split feats =====
    split_mat<<<2048, 256, 0, stream>>>(feat1, f1h, f1l, 8192LL * 1024 / 4);
    split_mat<<<2048, 256, 0, stream>>>(feat2, f2h, f2l, 8192LL * 1024 / 4);

    // ===== Phase 1: gconv layer 0 =====
    wsp(stream, W0u, 1024, 0, 2048, swh, swl);
    gsp(stream, 1, f1h, f1l, swh, swl, 2048, 1024, nullptr, T1h, T1l, b0u, 1);
    gsp(stream, 1, f2h, f2l, swh, swl, 2048, 1024, nullptr, T2h, T2l, b0u, 1);
    wsp(stream, W0a, 1024, 0, 2048, swh, swl);
    gsp(stream, 1, f1h, f1l, swh, swl, 2048, 1024, nullptr, T3h, T3l, b0a, 1);
    colnorm_k<<<32, 256, 0, stream>>>(A1, invA);
    colnorm_k<<<32, 256, 0, stream>>>(A2, invB);
    bgemm<false, true><<<bgrid, bblk, 0, stream>>>(A1, T3h, T3l, T1h, T1l, invA);
    gsp(stream, 1, f2h, f2l, swh, swl, 2048, 1024, nullptr, T3h, T3l, b0a, 1);
    bgemm<false, true><<<bgrid, bblk, 0, stream>>>(A2, T3h, T3l, T2h, T2l, invB);

    // ===== Phase 2: affinity 0 =====
    wsp(stream, Aaff0, 2048, 0, 1024, swh, swl);
    gsp(stream, 0, T1h, T1l, swh, swl, 1024, 2048, T3f + 0, nullptr, nullptr, nullptr, 0);
    wsp(stream, Aaff0, 2048, 1024, 1024, swh, swl);
    gsp(stream, 0, T1h, T1l, swh, swl, 1024, 2048, T3f + 1024, nullptr, nullptr, nullptr, 0);
    gemm_bt_f64<<<dim3(4, 4, 32), 256, 0, stream>>>(T3f, T2h, T2l, S);

    sk_fused<<<32, 1024, 0, stream>>>(S, n1);

    // ===== Phase 4: cross-graph update =====
    bgemm<false, false><<<bgrid, bblk, 0, stream>>>(S, T2h, T2l, T3h, T3l, nullptr);   // c1 = S @ emb2
    // new1 = [emb1 | c1] @ Wc + bc  (fused K=4096, single output pass)
    gemm_hyb<<<dim3(16, 64), 256, 0, stream>>>(T1h, T1l, T3h, T3l, Wc, 2048, 4096,
                                               T4h, T4l, 2048, bc);
    bgemm<true, false><<<bgrid, bblk, 0, stream>>>(S, T1h, T1l, T3h, T3l, nullptr);    // c2; S dead after
    wsp(stream, Wc, 2048, 0, 1024, swh, swl);
    gsp(stream, 1, T2h, T2l, swh, swl, 1024, 2048, nullptr, T1h + 0,    T1l + 0,    bc, 0);
    wsp(stream, Wc, 2048, 1024, 1024, swh, swl);
    gsp(stream, 1, T2h, T2l, swh, swl, 1024, 2048, nullptr, T1h + 1024, T1l + 1024, bc + 1024, 0);
    wsp(stream, Wc + 4194304, 2048, 0, 1024, swh, swl);
    gsp(stream, 2, T3h, T3l, swh, swl, 1024, 2048, nullptr, T1h + 0,    T1l + 0,    nullptr, 0);
    wsp(stream, Wc + 4194304, 2048, 1024, 1024, swh, swl);
    gsp(stream, 2, T3h, T3l, swh, swl, 1024, 2048, nullptr, T1h + 1024, T1l + 1024, nullptr, 0);

    // ===== Phase 5: gconv layer 1 =====
    wsp(stream, W1a, 2048, 0, 1024, swh, swl);
    gsp(stream, 1, T4h, T4l, swh, swl, 1024, 2048, nullptr, T2h + 0,    T2l + 0,    b1a, 1);
    wsp(stream, W1a, 2048, 1024, 1024, swh, swl);
    gsp(stream, 1, T4h, T4l, swh, swl, 1024, 2048, nullptr, T2h + 1024, T2l + 1024, b1a + 1024, 1);
    wsp(stream, W1u, 2048, 0, 1024, swh, swl);
    gsp(stream, 1, T4h, T4l, swh, swl, 1024, 2048, nullptr, T3h + 0,    T3l + 0,    b1u, 1);
    wsp(stream, W1u, 2048, 1024, 1024, swh, swl);
    gsp(stream, 1, T4h, T4l, swh, swl, 1024, 2048, nullptr, T3h + 1024, T3l + 1024, b1u + 1024, 1);
    colnorm_k<<<32, 256, 0, stream>>>(A1, inv1);
    bgemm<false, true><<<bgrid, bblk, 0, stream>>>(A1, T2h, T2l, T3h, T3l, inv1);
    wsp(stream, W1a, 2048, 0, 1024, swh, swl);
    gsp(stream, 1, T1h, T1l, swh, swl, 1024, 2048, nullptr, T2h + 0,    T2l + 0,    b1a, 1);
    wsp(stream, W1a, 2048, 1024, 1024, swh, swl);
    gsp(stream, 1, T1h, T1l, swh, swl, 1024, 2048, nullptr, T2h + 1024, T2l + 1024, b1a + 1024, 1);
    wsp(stream, W1u, 2048, 0, 1024, swh, swl);
    gsp(stream, 1, T1h, T1l, swh, swl, 1024, 2048, nullptr, T4h + 0,    T4l + 0,    b1u, 1);
    wsp(stream, W1u, 2048, 1024, 1024, swh, swl);
    gsp(stream, 1, T1h, T1l, swh, swl, 1024, 2048, nullptr, T4h + 1024, T4l + 1024, b1u + 1024, 1);
    colnorm_k<<<32, 256, 0, stream>>>(A2, inv2);
    bgemm<false, true><<<bgrid, bblk, 0, stream>>>(A2, T2h, T2l, T4h, T4l, inv2);

    // ===== Phase 6: affinity 1 =====
    wsp(stream, Aaff1, 2048, 0, 1024, swh, swl);
    gsp(stream, 0, T3h, T3l, swh, swl, 1024, 2048, T1f + 0, nullptr, nullptr, nullptr, 0);
    wsp(stream, Aaff1, 2048, 1024, 1024, swh, swl);
    gsp(stream, 0, T3h, T3l, swh, swl, 1024, 2048, T1f + 1024, nullptr, nullptr, nullptr, 0);
    gemm_bt_f64<<<dim3(4, 4, 32), 256, 0, stream>>>(T1f, T4h, T4l, S);

    sk_fused<<<32, 1024, 0, stream>>>(S, n1);
}

// Round 3
// 4614.573 us; speedup vs baseline: 1.1180x; 1.0964x over previous
//
#include <hip/hip_runtime.h>
#include <math.h>

#define NEGV -1e9f
#define SK_TAU 0.05f

typedef __attribute__((ext_vector_type(4))) float f32x4;
typedef __attribute__((ext_vector_type(8))) short short8;

#define GLDS(g, l) __builtin_amdgcn_global_load_lds( \
    (const __attribute__((address_space(1))) void*)(g), \
    (__attribute__((address_space(3))) void*)(l), 16, 0, 0)

// ---------------- bf16 split helpers ----------------
__device__ inline unsigned bf16rtn(float x) {
    unsigned u = __float_as_uint(x);
    return (u + 0x7FFFu + ((u >> 16) & 1u)) >> 16;
}
__device__ inline float bf2f(short h) {
    return __uint_as_float(((unsigned)(unsigned short)h) << 16);
}
__device__ inline void split1(float x, short& h, short& l) {
    unsigned hu = bf16rtn(x);
    h = (short)hu;
    float r = x - __uint_as_float(hu << 16);
    l = (short)(__float_as_uint(r) >> 16);
}
__device__ inline void cvt4(const float4 v, short4& h, short4& l) {
    unsigned h0 = bf16rtn(v.x), h1 = bf16rtn(v.y), h2 = bf16rtn(v.z), h3 = bf16rtn(v.w);
    h.x = (short)h0; h.y = (short)h1; h.z = (short)h2; h.w = (short)h3;
    float l0 = v.x - __uint_as_float(h0 << 16);
    float l1 = v.y - __uint_as_float(h1 << 16);
    float l2 = v.z - __uint_as_float(h2 << 16);
    float l3 = v.w - __uint_as_float(h3 << 16);
    l.x = (short)(__float_as_uint(l0) >> 16);
    l.y = (short)(__float_as_uint(l1) >> 16);
    l.z = (short)(__float_as_uint(l2) >> 16);
    l.w = (short)(__float_as_uint(l3) >> 16);
}
__device__ inline short8 pack8(const short4 a, const short4 b) {
    short8 r;
    r[0] = a.x; r[1] = a.y; r[2] = a.z; r[3] = a.w;
    r[4] = b.x; r[5] = b.y; r[6] = b.z; r[7] = b.w;
    return r;
}

// ---------------- inv column L1 norm ----------------
__global__ __launch_bounds__(256) void colnorm_k(const float* __restrict__ A,
                                                 float* __restrict__ inv)
{
    int idx = blockIdx.x * 256 + threadIdx.x;
    int b = idx >> 8, m = idx & 255;
    const float* p = A + (long long)b * 65536 + m;
    float s = 0.f;
    #pragma unroll 8
    for (int n = 0; n < 256; ++n) s += fabsf(p[n * 256]);
    inv[idx] = 1.f / fmaxf(s, 1e-12f);
}

// ---------------- fp32 -> split planes ----------------
__global__ __launch_bounds__(256) void split_mat(const float* __restrict__ X,
                                                 short* __restrict__ H,
                                                 short* __restrict__ L, long long n4)
{
    long long i = (long long)blockIdx.x * 256 + threadIdx.x;
    long long stride = (long long)gridDim.x * 256;
    for (; i < n4; i += stride) {
        float4 v = ((const float4*)X)[i];
        short4 h, l;
        cvt4(v, h, l);
        ((short4*)H)[i] = h;
        ((short4*)L)[i] = l;
    }
}

// =====================================================================
// Unified weight GEMM engine (split-bf16 MFMA, depth-2 double-buffered):
//   C = epi( [A1 | A2] @ Bf + bias ),  OM 0 = fp32 store, 1 = split store.
// A1,A2: pre-split [M][lda] planes; source switches at k = K1
// (single-source call sites pass A2 = A1, K1 = K).
// Bf: fp32 [K][2048] (weights / affinity), converted in-kernel.
// Per 32-K panel: one barrier; A via global_load_lds DMA into chunked
// layout; B reg-staged 2 panels ahead (named sets brA/brB, static idx)
// and written as 16 B/lane contiguous short8 (conflict-free; the old
// 8 B stride-16 short4 pattern was an 8-way bank conflict, 16.8M cycles).
// Chunk layout (per 16col x 32k chunk of 512 shorts): [k>>3][col&15][k&7].
// =====================================================================
template <int OM>
__global__ __launch_bounds__(256, 2) void gemm_w(
    const short* __restrict__ A1h, const short* __restrict__ A1l,
    const short* __restrict__ A2h, const short* __restrict__ A2l,
    int K1, int lda,
    const float* __restrict__ Bf, int K,
    float* __restrict__ Cf, short* __restrict__ Ch, short* __restrict__ Cl,
    const float* __restrict__ bias, int relu)
{
    __shared__ alignas(16) short lds[2][16384];   // [buf][Ah|Al|Bh|Bl x 4096]

    const int tid = threadIdx.x;
    const int wave = tid >> 6, L = tid & 63;
    const int m0 = blockIdx.y * 128, n0 = blockIdx.x * 128;
    const int wm = (wave & 1) * 64, wn = (wave >> 1) * 64;
    const int lm = L & 15, lh = (L >> 4) * 8;
    const int c0 = wave * 2;

    long long grow[2];
    #pragma unroll
    for (int c = 0; c < 2; ++c)
        grow[c] = (long long)(m0 + (c0 + c) * 16 + lm) * lda + lh;

    // B: thread owns col bcol, k-half bkh (k 0-15 or 16-31 of each panel)
    const int bcol = tid & 127, bkh = tid >> 7;
    const float* bp = Bf + (long long)(bkh * 16) * 2048 + n0 + bcol;
    const int bws = (bcol >> 4) * 512 + (bcol & 15) * 8 + bkh * 256;

    f32x4 acc[4][4];
    #pragma unroll
    for (int i = 0; i < 4; ++i)
        #pragma unroll
        for (int j = 0; j < 4; ++j)
            acc[i][j] = (f32x4){0.f, 0.f, 0.f, 0.f};

    auto STAGE = [&](short* buf, int k0) {
        const short *sh, *sl;
        int ko;
        if (k0 < K1) { sh = A1h; sl = A1l; ko = k0; }
        else         { sh = A2h; sl = A2l; ko = k0 - K1; }
        #pragma unroll
        for (int c = 0; c < 2; ++c) {
            const int so = (c0 + c) * 512;
            GLDS(sh + grow[c] + ko, buf + so);
            GLDS(sl + grow[c] + ko, buf + 4096 + so);
        }
    };
    auto LOADB = [&](float br[16], int k0) {
        #pragma unroll
        for (int j = 0; j < 16; ++j)
            br[j] = bp[((long long)k0 + j) * 2048];
    };
    auto WRITEB = [&](short* buf, const float br[16]) {
        #pragma unroll
        for (int ks = 0; ks < 2; ++ks) {
            float4 v0 = {br[ks * 8 + 0], br[ks * 8 + 1], br[ks * 8 + 2], br[ks * 8 + 3]};
            float4 v1 = {br[ks * 8 + 4], br[ks * 8 + 5], br[ks * 8 + 6], br[ks * 8 + 7]};
            short4 h0, l0, h1, l1;
            cvt4(v0, h0, l0);
            cvt4(v1, h1, l1);
            *(short8*)(buf + 8192  + bws + ks * 128) = pack8(h0, h1);
            *(short8*)(buf + 12288 + bws + ks * 128) = pack8(l0, l1);
        }
    };

    const int ab = (wm >> 4) * 512 + L * 8;
    const int bb = (wn >> 4) * 512 + L * 8;
    auto COMPUTE = [&](const short* buf) {
        const short* AhS = buf;
        const short* AlS = buf + 4096;
        const short* BhS = buf + 8192;
        const short* BlS = buf + 12288;
        short8 AF[4], ALF[4], BFr[4], BLF[4];
        #pragma unroll
        for (int t = 0; t < 4; ++t) {
            AF[t]  = *(const short8*)(AhS + ab + t * 512);
            ALF[t] = *(const short8*)(AlS + ab + t * 512);
            BFr[t] = *(const short8*)(BhS + bb + t * 512);
            BLF[t] = *(const short8*)(BlS + bb + t * 512);
        }
        #pragma unroll
        for (int ti = 0; ti < 4; ++ti)
            #pragma unroll
            for (int tj = 0; tj < 4; ++tj) {
                acc[ti][tj] = __builtin_amdgcn_mfma_f32_16x16x32_bf16(AF[ti],  BFr[tj], acc[ti][tj], 0, 0, 0);
                acc[ti][tj] = __builtin_amdgcn_mfma_f32_16x16x32_bf16(AF[ti],  BLF[tj], acc[ti][tj], 0, 0, 0);
                acc[ti][tj] = __builtin_amdgcn_mfma_f32_16x16x32_bf16(ALF[ti], BFr[tj], acc[ti][tj], 0, 0, 0);
            }
    };

    const int NT = K >> 5;          // panels; always even here (K mult of 64)
    float brA[16], brB[16];

    // prologue: panel0 -> buf0 (A DMA + B regs->LDS); panels 1,2 -> regs
    LOADB(brA, 0);
    STAGE(lds[0], 0);
    LOADB(brB, 32);
    WRITEB(lds[0], brA);
    LOADB(brA, 64);

    for (int t = 0; t < NT; t += 2) {
        // even body: consume buf0 (panel t), fill buf1 (panel t+1)
        __syncthreads();
        {
            STAGE(lds[1], (t + 1) << 5);        // t+1 <= NT-1 (NT even)
            WRITEB(lds[1], brB);
        }
        if (t + 3 < NT) LOADB(brB, (t + 3) << 5);
        COMPUTE(lds[0]);

        // odd body: consume buf1 (panel t+1), fill buf0 (panel t+2)
        __syncthreads();
        if (t + 2 < NT) {
            STAGE(lds[0], (t + 2) << 5);
            WRITEB(lds[0], brA);
        }
        if (t + 4 < NT) LOADB(brA, (t + 4) << 5);
        COMPUTE(lds[1]);
    }

    // ---- epilogue: C/D layout col = lane&15, row = (lane>>4)*4 + reg ----
    const int lcol = L & 15, lrow = (L >> 4) * 4;
    float bv[4];
    #pragma unroll
    for (int tj = 0; tj < 4; ++tj)
        bv[tj] = bias ? bias[n0 + wn + tj * 16 + lcol] : 0.f;

    #pragma unroll
    for (int ti = 0; ti < 4; ++ti) {
        #pragma unroll
        for (int r = 0; r < 4; ++r) {
            int gr = m0 + wm + ti * 16 + lrow + r;
            #pragma unroll
            for (int tj = 0; tj < 4; ++tj) {
                int gcol = n0 + wn + tj * 16 + lcol;
                float v = acc[ti][tj][r] + bv[tj];
                if (relu) v = fmaxf(v, 0.f);
                long long idx = (long long)gr * 2048 + gcol;
                if (OM == 0) {
                    Cf[idx] = v;
                } else {
                    short hh, ll;
                    split1(v, hh, ll);
                    Ch[idx] = hh;
                    Cl[idx] = ll;
                }
            }
        }
    }
}

// ---------------- batched fp32 VALU GEMM (256x2048x256 per batch) ----------------
template <bool TA, bool ACC>
__global__ __launch_bounds__(256, 2) void bgemm(
    const float* __restrict__ A,
    const short* __restrict__ Bh_, const short* __restrict__ Bl_,
    short* __restrict__ Ch, short* __restrict__ Cl,
    const float* __restrict__ colscale)
{
    __shared__ float As[16][132];
    __shared__ float Bs[16][132];

    const int N = 2048;
    const long long sB = 524288;
    int z = blockIdx.z;
    const float* Az = A + (long long)z * 65536;
    const float* cs = colscale ? colscale + z * 256 : nullptr;

    int n0 = blockIdx.x * 128, m0 = blockIdx.y * 128;
    int tid = threadIdx.x;
    int tx = tid & 15, ty = tid >> 4;

    float accv[8][8];
    #pragma unroll
    for (int i = 0; i < 8; ++i)
        #pragma unroll
        for (int j = 0; j < 8; ++j) accv[i][j] = 0.f;

    for (int k0 = 0; k0 < 256; k0 += 16) {
        if (!TA) {
            #pragma unroll
            for (int i = 0; i < 2; ++i) {
                int lin = tid + i * 256;
                int r  = lin >> 2;
                int c4 = (lin & 3) * 4;
                float4 v = *(const float4*)(Az + (long long)(m0 + r) * 256 + k0 + c4);
                if (cs) {
                    v.x *= cs[k0 + c4 + 0]; v.y *= cs[k0 + c4 + 1];
                    v.z *= cs[k0 + c4 + 2]; v.w *= cs[k0 + c4 + 3];
                }
                As[c4 + 0][r] = v.x; As[c4 + 1][r] = v.y;
                As[c4 + 2][r] = v.z; As[c4 + 3][r] = v.w;
            }
        } else {
            #pragma unroll
            for (int i = 0; i < 2; ++i) {
                int lin = tid + i * 256;
                int kk = lin >> 5;
                int m4 = (lin & 31) * 4;
                *(float4*)&As[kk][m4] =
                    *(const float4*)(Az + (long long)(k0 + kk) * 256 + m0 + m4);
            }
        }
        #pragma unroll
        for (int i = 0; i < 2; ++i) {
            int lin = tid + i * 256;
            int kk = lin >> 5;
            int n4 = (lin & 31) * 4;
            long long off = (long long)z * sB + (long long)(k0 + kk) * N + n0 + n4;
            short4 h = *(const short4*)(Bh_ + off);
            short4 l = *(const short4*)(Bl_ + off);
            Bs[kk][n4 + 0] = bf2f(h.x) + bf2f(l.x);
            Bs[kk][n4 + 1] = bf2f(h.y) + bf2f(l.y);
            Bs[kk][n4 + 2] = bf2f(h.z) + bf2f(l.z);
            Bs[kk][n4 + 3] = bf2f(h.w) + bf2f(l.w);
        }
        __syncthreads();

        #pragma unroll
        for (int kk = 0; kk < 16; ++kk) {
            float a[8], b[8];
            *(float4*)&a[0] = *(const float4*)&As[kk][ty * 8];
            *(float4*)&a[4] = *(const float4*)&As[kk][ty * 8 + 4];
            *(float4*)&b[0] = *(const float4*)&Bs[kk][tx * 8];
            *(float4*)&b[4] = *(const float4*)&Bs[kk][tx * 8 + 4];
            #pragma unroll
            for (int i = 0; i < 8; ++i)
                #pragma unroll
                for (int j = 0; j < 8; ++j)
                    accv[i][j] = fmaf(a[i], b[j], accv[i][j]);
        }
        __syncthreads();
    }

    #pragma unroll
    for (int i = 0; i < 8; ++i) {
        int rowl = m0 + ty * 8 + i;
        long long base = (long long)z * sB + (long long)rowl * N;
        #pragma unroll
        for (int j = 0; j < 8; ++j) {
            int col = n0 + tx * 8 + j;
            long long idx = base + col;
            float v = accv[i][j];
            if (ACC) v += bf2f(Ch[idx]) + bf2f(Cl[idx]);
            short hh, ll;
            split1(v, hh, ll);
            Ch[idx] = hh;
            Cl[idx] = ll;
        }
    }
}

// ---------------- fp64-accumulate affinity GEMM ----------------
__global__ __launch_bounds__(256) void gemm_bt_f64(
    const float* __restrict__ A,
    const short* __restrict__ Bh_, const short* __restrict__ Bl_,
    float* __restrict__ C)
{
    __shared__ float As[16][65];
    __shared__ float Bs[16][65];

    const int K = 2048;
    int z = blockIdx.z;
    const float* Az = A + (long long)z * 524288;
    C += (long long)z * 65536;

    int n0 = blockIdx.x * 64;
    int m0 = blockIdx.y * 64;
    int tid = threadIdx.x;
    int tx = tid & 15;
    int ty = tid >> 4;

    double acc[4][4];
    #pragma unroll
    for (int i = 0; i < 4; ++i)
        #pragma unroll
        for (int j = 0; j < 4; ++j) acc[i][j] = 0.0;

    int r  = tid >> 2;
    int c4 = (tid & 3) * 4;

    for (int k0 = 0; k0 < K; k0 += 16) {
        {
            const float4 v = *(const float4*)(Az + (long long)(m0 + r) * K + k0 + c4);
            As[c4 + 0][r] = v.x; As[c4 + 1][r] = v.y;
            As[c4 + 2][r] = v.z; As[c4 + 3][r] = v.w;
        }
        {
            long long off = (long long)z * 524288 + (long long)(n0 + r) * K + k0 + c4;
            short4 h = *(const short4*)(Bh_ + off);
            short4 l = *(const short4*)(Bl_ + off);
            Bs[c4 + 0][r] = bf2f(h.x) + bf2f(l.x);
            Bs[c4 + 1][r] = bf2f(h.y) + bf2f(l.y);
            Bs[c4 + 2][r] = bf2f(h.z) + bf2f(l.z);
            Bs[c4 + 3][r] = bf2f(h.w) + bf2f(l.w);
        }
        __syncthreads();

        #pragma unroll
        for (int kk = 0; kk < 16; ++kk) {
            double a[4], b[4];
            #pragma unroll
            for (int i = 0; i < 4; ++i) a[i] = (double)As[kk][ty + 16 * i];
            #pragma unroll
            for (int j = 0; j < 4; ++j) b[j] = (double)Bs[kk][tx + 16 * j];
            #pragma unroll
            for (int i = 0; i < 4; ++i)
                #pragma unroll
                for (int j = 0; j < 4; ++j)
                    acc[i][j] = fma(a[i], b[j], acc[i][j]);
        }
        __syncthreads();
    }

    #pragma unroll
    for (int i = 0; i < 4; ++i) {
        int rowl = m0 + ty + 16 * i;
        #pragma unroll
        for (int j = 0; j < 4; ++j)
            C[(long long)rowl * 256 + n0 + tx + 16 * j] = (float)acc[i][j];
    }
}

// =====================================================================
// Fused Sinkhorn: one 1024-thread block per batch; S register-resident.
// =====================================================================
__global__ __launch_bounds__(1024, 4) void sk_fused(float* __restrict__ S,
                                                    const int* __restrict__ n1)
{
    __shared__ float pmax[16][256];
    __shared__ float psum[16][256];
    __shared__ float lseS[256];

    const int b = blockIdx.x;
    const int tid = threadIdx.x;
    const int w = tid >> 6, l = tid & 63;
    const int lim = n1[b];
    float* Sb = S + (long long)b * 65536;

    float4 v[16];
    #pragma unroll
    for (int r = 0; r < 16; ++r) {
        int n = w * 16 + r;
        if (n < lim) {
            float4 x = *(const float4*)(Sb + n * 256 + l * 4);
            v[r].x = x.x / SK_TAU; v[r].y = x.y / SK_TAU;
            v[r].z = x.z / SK_TAU; v[r].w = x.w / SK_TAU;
        } else {
            v[r] = (float4){NEGV, NEGV, NEGV, NEGV};
        }
    }

    for (int it = 0; it < 10; ++it) {
        if ((it & 1) == 0) {
            #pragma unroll
            for (int r = 0; r < 16; ++r) {
                if (w * 16 + r >= lim) continue;
                float m = fmaxf(fmaxf(v[r].x, v[r].y), fmaxf(v[r].z, v[r].w));
                #pragma unroll
                for (int off = 1; off < 64; off <<= 1) m = fmaxf(m, __shfl_xor(m, off));
                float s = expf(v[r].x - m) + expf(v[r].y - m) +
                          expf(v[r].z - m) + expf(v[r].w - m);
                #pragma unroll
                for (int off = 1; off < 64; off <<= 1) s += __shfl_xor(s, off);
                float lse = m + logf(s);
                v[r].x -= lse; v[r].y -= lse; v[r].z -= lse; v[r].w -= lse;
            }
        } else {
            float cm[4] = {-3.4e38f, -3.4e38f, -3.4e38f, -3.4e38f};
            #pragma unroll
            for (int r = 0; r < 16; ++r) {
                cm[0] = fmaxf(cm[0], v[r].x); cm[1] = fmaxf(cm[1], v[r].y);
                cm[2] = fmaxf(cm[2], v[r].z); cm[3] = fmaxf(cm[3], v[r].w);
            }
            float cs[4] = {0.f, 0.f, 0.f, 0.f};
            #pragma unroll
            for (int r = 0; r < 16; ++r) {
                cs[0] += expf(v[r].x - cm[0]); cs[1] += expf(v[r].y - cm[1]);
                cs[2] += expf(v[r].z - cm[2]); cs[3] += expf(v[r].w - cm[3]);
            }
            #pragma unroll
            for (int j = 0; j < 4; ++j) {
                pmax[w][l * 4 + j] = cm[j];
                psum[w][l * 4 + j] = cs[j];
            }
            __syncthreads();
            if (tid < 256) {
                float m = -3.4e38f, s = 0.f;
                #pragma unroll
                for (int ww = 0; ww < 16; ++ww) {
                    float pm = pmax[ww][tid], ps = psum[ww][tid];
                    float nm = fmaxf(m, pm);
                    s = s * expf(m - nm) + ps * expf(pm - nm);
                    m = nm;
                }
                lseS[tid] = m + logf(s);
            }
            __syncthreads();
            float l0 = lseS[l * 4 + 0], l1 = lseS[l * 4 + 1];
            float l2 = lseS[l * 4 + 2], l3 = lseS[l * 4 + 3];
            #pragma unroll
            for (int r = 0; r < 16; ++r) {
                if (w * 16 + r >= lim) continue;
                v[r].x -= l0; v[r].y -= l1; v[r].z -= l2; v[r].w -= l3;
            }
        }
    }

    #pragma unroll
    for (int r = 0; r < 16; ++r) {
        int n = w * 16 + r;
        float4 o;
        if (n < lim) {
            o.x = expf(v[r].x); o.y = expf(v[r].y);
            o.z = expf(v[r].z); o.w = expf(v[r].w);
        } else {
            o = (float4){0.f, 0.f, 0.f, 0.f};
        }
        *(float4*)(Sb + n * 256 + l * 4) = o;
    }
}

// ---------------- launch wrappers ----------------
static void gw(hipStream_t st, int om, const short* Ah, const short* Al, int lda,
               const float* Bf, int K,
               float* Cf, short* Ch, short* Cl, const float* bias, int relu)
{
    dim3 grid(16, 64), block(256);
    if (om == 0)
        gemm_w<0><<<grid, block, 0, st>>>(Ah, Al, Ah, Al, K, lda, Bf, K,
                                          Cf, nullptr, nullptr, bias, relu);
    else
        gemm_w<1><<<grid, block, 0, st>>>(Ah, Al, Ah, Al, K, lda, Bf, K,
                                          nullptr, Ch, Cl, bias, relu);
}

static void gwcat(hipStream_t st, const short* A1h, const short* A1l,
                  const short* A2h, const short* A2l,
                  const float* Bf, short* Ch, short* Cl, const float* bias)
{
    dim3 grid(16, 64), block(256);
    gemm_w<1><<<grid, block, 0, st>>>(A1h, A1l, A2h, A2l, 2048, 2048, Bf, 4096,
                                      nullptr, Ch, Cl, bias, 0);
}

// ---------------- driver ----------------
extern "C" void kernel_launch(void* const* d_in, const int* in_sizes, int n_in,
                              void* d_out, int out_size, void* d_ws, size_t ws_size,
                              hipStream_t stream)
{
    const float* feat1 = (const float*)d_in[0];
    const float* feat2 = (const float*)d_in[1];
    const float* A1    = (const float*)d_in[2];
    const float* A2    = (const float*)d_in[3];
    const int*   n1    = (const int*)d_in[4];
    const float* W0a = (const float*)d_in[8];  const float* b0a = (const float*)d_in[9];
    const float* W0u = (const float*)d_in[10]; const float* b0u = (const float*)d_in[11];
    const float* W1a = (const float*)d_in[12]; const float* b1a = (const float*)d_in[13];
    const float* W1u = (const float*)d_in[14]; const float* b1u = (const float*)d_in[15];
    const float* Wc  = (const float*)d_in[16]; const float* bc  = (const float*)d_in[17];
    const float* Aaff0 = (const float*)d_in[18];
    const float* Aaff1 = (const float*)d_in[19];

    const long long TSZ = 16777216LL;
    const long long PL  = 16777216LL;
    const long long PF  = 8388608LL;

    float* T1f = (float*)d_ws;
    float* T2f = T1f + TSZ;
    float* T3f = T2f + TSZ;
    float* T4f = T3f + TSZ;
    short *T1h = (short*)T1f, *T1l = T1h + PL;
    short *T2h = (short*)T2f, *T2l = T2h + PL;
    short *T3h = (short*)T3f, *T3l = T3h + PL;
    short *T4h = (short*)T4f, *T4l = T4h + PL;

    short* f1h = (short*)T4f;      short* f1l = f1h + PF;
    short* f2h = f1h + 2 * PF;     short* f2l = f1h + 3 * PF;
    float* invA = (float*)T4f;     // overlaps f1h rows 0-15: written only
    float* invB = invA + 8192;     // after the last f1 read (see ordering)

    float* S    = (float*)d_out;
    float* inv1 = S;
    float* inv2 = S + 8192;

    dim3 bgrid(16, 2, 32), bblk(256);

    // ===== Phase 0: split feats =====
    split_mat<<<2048, 256, 0, stream>>>(feat1, f1h, f1l, 8192LL * 1024 / 4);
    split_mat<<<2048, 256, 0, stream>>>(feat2, f2h, f2l, 8192LL * 1024 / 4);

    // ===== Phase 1: gconv layer 0 (K=1024, lda=1024) =====
    gw(stream, 1, f1h, f1l, 1024, W0u, 1024, nullptr, T1h, T1l, b0u, 1);
    gw(stream, 1, f2h, f2l, 1024, W0u, 1024, nullptr, T2h, T2l, b0u, 1);
    gw(stream, 1, f1h, f1l, 1024, W0a, 1024, nullptr, T3h, T3l, b0a, 1);   // last f1 read
    colnorm_k<<<32, 256, 0, stream>>>(A1, invA);
    colnorm_k<<<32, 256, 0, stream>>>(A2, invB);
    bgemm<false, true><<<bgrid, bblk, 0, stream>>>(A1, T3h, T3l, T1h, T1l, invA);
    gw(stream, 1, f2h, f2l, 1024, W0a, 1024, nullptr, T3h, T3l, b0a, 1);
    bgemm<false, true><<<bgrid, bblk, 0, stream>>>(A2, T3h, T3l, T2h, T2l, invB);

    // ===== Phase 2: affinity 0 =====
    gw(stream, 0, T1h, T1l, 2048, Aaff0, 2048, T3f, nullptr, nullptr, nullptr, 0);
    gemm_bt_f64<<<dim3(4, 4, 32), 256, 0, stream>>>(T3f, T2h, T2l, S);

    sk_fused<<<32, 1024, 0, stream>>>(S, n1);

    // ===== Phase 4: cross-graph update =====
    bgemm<false, false><<<bgrid, bblk, 0, stream>>>(S, T2h, T2l, T3h, T3l, nullptr);  // c1 = S @ emb2
    gwcat(stream, T1h, T1l, T3h, T3l, Wc, T4h, T4l, bc);   // new1 = [emb1|c1]@Wc+bc
    bgemm<true, false><<<bgrid, bblk, 0, stream>>>(S, T1h, T1l, T3h, T3l, nullptr);   // c2 = S^T @ emb1
    gwcat(stream, T2h, T2l, T3h, T3l, Wc, T1h, T1l, bc);   // new2 = [emb2|c2]@Wc+bc

    // ===== Phase 5: gconv layer 1 (K=2048, lda=2048) =====
    gw(stream, 1, T4h, T4l, 2048, W1a, 2048, nullptr, T2h, T2l, b1a, 1);   // a-path g1
    gw(stream, 1, T4h, T4l, 2048, W1u, 2048, nullptr, T3h, T3l, b1u, 1);   // u-path g1
    colnorm_k<<<32, 256, 0, stream>>>(A1, inv1);
    bgemm<false, true><<<bgrid, bblk, 0, stream>>>(A1, T2h, T2l, T3h, T3l, inv1);     // emb1' = T3
    gw(stream, 1, T1h, T1l, 2048, W1a, 2048, nullptr, T2h, T2l, b1a, 1);   // a-path g2
    gw(stream, 1, T1h, T1l, 2048, W1u, 2048, nullptr, T4h, T4l, b1u, 1);   // u-path g2
    colnorm_k<<<32, 256, 0, stream>>>(A2, inv2);
    bgemm<false, true><<<bgrid, bblk, 0, stream>>>(A2, T2h, T2l, T4h, T4l, inv2);     // emb2' = T4

    // ===== Phase 6: affinity 1 =====
    gw(stream, 0, T3h, T3l, 2048, Aaff1, 2048, T1f, nullptr, nullptr, nullptr, 0);
    gemm_bt_f64<<<dim3(4, 4, 32), 256, 0, stream>>>(T1f, T4h, T4l, S);

    sk_fused<<<32, 1024, 0, stream>>>(S, n1);
}

// Round 6
// 4339.633 us; speedup vs baseline: 1.1888x; 1.0634x over previous
//
#include <hip/hip_runtime.h>
#include <math.h>

#define NEGV -1e9f
#define SK_TAU 0.05f

typedef __attribute__((ext_vector_type(4))) float f32x4;
typedef __attribute__((ext_vector_type(8))) short short8;

#define GLDS(g, l) __builtin_amdgcn_global_load_lds( \
    (const __attribute__((address_space(1))) void*)(g), \
    (__attribute__((address_space(3))) void*)(l), 16, 0, 0)

// ---------------- bf16 split helpers ----------------
__device__ inline unsigned bf16rtn(float x) {
    unsigned u = __float_as_uint(x);
    return (u + 0x7FFFu + ((u >> 16) & 1u)) >> 16;
}
__device__ inline float bf2f(short h) {
    return __uint_as_float(((unsigned)(unsigned short)h) << 16);
}
__device__ inline void split1(float x, short& h, short& l) {
    unsigned hu = bf16rtn(x);
    h = (short)hu;
    float r = x - __uint_as_float(hu << 16);
    l = (short)(__float_as_uint(r) >> 16);
}
__device__ inline void cvt4(const float4 v, short4& h, short4& l) {
    unsigned h0 = bf16rtn(v.x), h1 = bf16rtn(v.y), h2 = bf16rtn(v.z), h3 = bf16rtn(v.w);
    h.x = (short)h0; h.y = (short)h1; h.z = (short)h2; h.w = (short)h3;
    float l0 = v.x - __uint_as_float(h0 << 16);
    float l1 = v.y - __uint_as_float(h1 << 16);
    float l2 = v.z - __uint_as_float(h2 << 16);
    float l3 = v.w - __uint_as_float(h3 << 16);
    l.x = (short)(__float_as_uint(l0) >> 16);
    l.y = (short)(__float_as_uint(l1) >> 16);
    l.z = (short)(__float_as_uint(l2) >> 16);
    l.w = (short)(__float_as_uint(l3) >> 16);
}
__device__ inline short8 pack8(const short4 a, const short4 b) {
    short8 r;
    r[0] = a.x; r[1] = a.y; r[2] = a.z; r[3] = a.w;
    r[4] = b.x; r[5] = b.y; r[6] = b.z; r[7] = b.w;
    return r;
}

// ---------------- inv column L1 norm ----------------
__global__ __launch_bounds__(256) void colnorm_k(const float* __restrict__ A,
                                                 float* __restrict__ inv)
{
    int idx = blockIdx.x * 256 + threadIdx.x;
    int b = idx >> 8, m = idx & 255;
    const float* p = A + (long long)b * 65536 + m;
    float s = 0.f;
    #pragma unroll 8
    for (int n = 0; n < 256; ++n) s += fabsf(p[n * 256]);
    inv[idx] = 1.f / fmaxf(s, 1e-12f);
}

// ---------------- fp32 -> split planes ----------------
__global__ __launch_bounds__(256) void split_mat(const float* __restrict__ X,
                                                 short* __restrict__ H,
                                                 short* __restrict__ L, long long n4)
{
    long long i = (long long)blockIdx.x * 256 + threadIdx.x;
    long long stride = (long long)gridDim.x * 256;
    for (; i < n4; i += stride) {
        float4 v = ((const float4*)X)[i];
        short4 h, l;
        cvt4(v, h, l);
        ((short4*)H)[i] = h;
        ((short4*)L)[i] = l;
    }
}

// =====================================================================
// Unified weight GEMM engine (split-bf16 MFMA, depth-2 double-buffered):
//   C = epi( [A1 | A2] @ Bf + bias ),  OM 0 = fp32 store, 1 = split store.
// A via global_load_lds DMA; B (fp32 weight) reg-staged 2 panels ahead,
// conflict-free short8 LDS writes. One barrier per 32-K panel.
// =====================================================================
template <int OM>
__global__ __launch_bounds__(256, 2) void gemm_w(
    const short* __restrict__ A1h, const short* __restrict__ A1l,
    const short* __restrict__ A2h, const short* __restrict__ A2l,
    int K1, int lda,
    const float* __restrict__ Bf, int K,
    float* __restrict__ Cf, short* __restrict__ Ch, short* __restrict__ Cl,
    const float* __restrict__ bias, int relu)
{
    __shared__ alignas(16) short lds[2][16384];   // [buf][Ah|Al|Bh|Bl x 4096]

    const int tid = threadIdx.x;
    const int wave = tid >> 6, L = tid & 63;
    const int m0 = blockIdx.y * 128, n0 = blockIdx.x * 128;
    const int wm = (wave & 1) * 64, wn = (wave >> 1) * 64;
    const int lm = L & 15, lh = (L >> 4) * 8;
    const int c0 = wave * 2;

    long long grow[2];
    #pragma unroll
    for (int c = 0; c < 2; ++c)
        grow[c] = (long long)(m0 + (c0 + c) * 16 + lm) * lda + lh;

    const int bcol = tid & 127, bkh = tid >> 7;
    const float* bp = Bf + (long long)(bkh * 16) * 2048 + n0 + bcol;
    const int bws = (bcol >> 4) * 512 + (bcol & 15) * 8 + bkh * 256;

    f32x4 acc[4][4];
    #pragma unroll
    for (int i = 0; i < 4; ++i)
        #pragma unroll
        for (int j = 0; j < 4; ++j)
            acc[i][j] = (f32x4){0.f, 0.f, 0.f, 0.f};

    auto STAGE = [&](short* buf, int k0) {
        const short *sh, *sl;
        int ko;
        if (k0 < K1) { sh = A1h; sl = A1l; ko = k0; }
        else         { sh = A2h; sl = A2l; ko = k0 - K1; }
        #pragma unroll
        for (int c = 0; c < 2; ++c) {
            const int so = (c0 + c) * 512;
            GLDS(sh + grow[c] + ko, buf + so);
            GLDS(sl + grow[c] + ko, buf + 4096 + so);
        }
    };
    auto LOADB = [&](float br[16], int k0) {
        #pragma unroll
        for (int j = 0; j < 16; ++j)
            br[j] = bp[((long long)k0 + j) * 2048];
    };
    auto WRITEB = [&](short* buf, const float br[16]) {
        #pragma unroll
        for (int ks = 0; ks < 2; ++ks) {
            float4 v0 = {br[ks * 8 + 0], br[ks * 8 + 1], br[ks * 8 + 2], br[ks * 8 + 3]};
            float4 v1 = {br[ks * 8 + 4], br[ks * 8 + 5], br[ks * 8 + 6], br[ks * 8 + 7]};
            short4 h0, l0, h1, l1;
            cvt4(v0, h0, l0);
            cvt4(v1, h1, l1);
            *(short8*)(buf + 8192  + bws + ks * 128) = pack8(h0, h1);
            *(short8*)(buf + 12288 + bws + ks * 128) = pack8(l0, l1);
        }
    };

    const int ab = (wm >> 4) * 512 + L * 8;
    const int bb = (wn >> 4) * 512 + L * 8;
    auto COMPUTE = [&](const short* buf) {
        const short* AhS = buf;
        const short* AlS = buf + 4096;
        const short* BhS = buf + 8192;
        const short* BlS = buf + 12288;
        short8 AF[4], ALF[4], BFr[4], BLF[4];
        #pragma unroll
        for (int t = 0; t < 4; ++t) {
            AF[t]  = *(const short8*)(AhS + ab + t * 512);
            ALF[t] = *(const short8*)(AlS + ab + t * 512);
            BFr[t] = *(const short8*)(BhS + bb + t * 512);
            BLF[t] = *(const short8*)(BlS + bb + t * 512);
        }
        #pragma unroll
        for (int ti = 0; ti < 4; ++ti)
            #pragma unroll
            for (int tj = 0; tj < 4; ++tj) {
                acc[ti][tj] = __builtin_amdgcn_mfma_f32_16x16x32_bf16(AF[ti],  BFr[tj], acc[ti][tj], 0, 0, 0);
                acc[ti][tj] = __builtin_amdgcn_mfma_f32_16x16x32_bf16(AF[ti],  BLF[tj], acc[ti][tj], 0, 0, 0);
                acc[ti][tj] = __builtin_amdgcn_mfma_f32_16x16x32_bf16(ALF[ti], BFr[tj], acc[ti][tj], 0, 0, 0);
            }
    };

    const int NT = K >> 5;          // panels; always even here (K mult of 64)
    float brA[16], brB[16];

    LOADB(brA, 0);
    STAGE(lds[0], 0);
    LOADB(brB, 32);
    WRITEB(lds[0], brA);
    LOADB(brA, 64);

    for (int t = 0; t < NT; t += 2) {
        __syncthreads();
        {
            STAGE(lds[1], (t + 1) << 5);
            WRITEB(lds[1], brB);
        }
        if (t + 3 < NT) LOADB(brB, (t + 3) << 5);
        COMPUTE(lds[0]);

        __syncthreads();
        if (t + 2 < NT) {
            STAGE(lds[0], (t + 2) << 5);
            WRITEB(lds[0], brA);
        }
        if (t + 4 < NT) LOADB(brA, (t + 4) << 5);
        COMPUTE(lds[1]);
    }

    const int lcol = L & 15, lrow = (L >> 4) * 4;
    float bv[4];
    #pragma unroll
    for (int tj = 0; tj < 4; ++tj)
        bv[tj] = bias ? bias[n0 + wn + tj * 16 + lcol] : 0.f;

    #pragma unroll
    for (int ti = 0; ti < 4; ++ti) {
        #pragma unroll
        for (int r = 0; r < 4; ++r) {
            int gr = m0 + wm + ti * 16 + lrow + r;
            #pragma unroll
            for (int tj = 0; tj < 4; ++tj) {
                int gcol = n0 + wn + tj * 16 + lcol;
                float v = acc[ti][tj][r] + bv[tj];
                if (relu) v = fmaxf(v, 0.f);
                long long idx = (long long)gr * 2048 + gcol;
                if (OM == 0) {
                    Cf[idx] = v;
                } else {
                    short hh, ll;
                    split1(v, hh, ll);
                    Ch[idx] = hh;
                    Cl[idx] = ll;
                }
            }
        }
    }
}

// =====================================================================
// Batched MFMA GEMM replacing the fp32 VALU bgemm:
//   per batch z: C[256][2048] = A(256x256, fp32, opt colscale) @ B(256x2048 split)
//   TA: A'[m][k] = A[k][m] (c2 = S^T @ emb1).   ACC: C += existing (split RMW).
// Same 128x128-tile / chunked-LDS / 1-barrier-per-panel engine as gemm_w;
// BOTH operands reg-staged (B is [k][n]-stored so global_load_lds can't
// produce the k-contiguous fragment layout - rule: swizzle both sides or
// neither). K=256 -> 8 panels, fully unrolled, statically-indexed bufs.
// =====================================================================
template <bool TA, bool ACC>
__global__ __launch_bounds__(256, 2) void bgemm_m(
    const float* __restrict__ A,
    const short* __restrict__ Bh_, const short* __restrict__ Bl_,
    short* __restrict__ Ch, short* __restrict__ Cl,
    const float* __restrict__ colscale)
{
    __shared__ alignas(16) short lds[2][16384];   // [buf][Ah|Al|Bh|Bl x 4096]

    const int tid = threadIdx.x;
    const int wave = tid >> 6, L = tid & 63;
    const int z = blockIdx.z;
    const int n0 = blockIdx.x * 128, m0 = blockIdx.y * 128;
    const int wm = (wave & 1) * 64, wn = (wave >> 1) * 64;
    const long long sB = 524288;
    const float* Az = A + (long long)z * 65536;
    const float* cs = colscale ? colscale + z * 256 : nullptr;

    // staging roles: thread owns one row/col of the 128-tile + one k-half
    const int arow = tid & 127, akh = tid >> 7;
    const int aws = (arow >> 4) * 512 + (arow & 15) * 8 + akh * 256;
    const int bws = aws;   // same formula (bcol==arow, bkh==akh)

    f32x4 acc[4][4];
    #pragma unroll
    for (int i = 0; i < 4; ++i)
        #pragma unroll
        for (int j = 0; j < 4; ++j)
            acc[i][j] = (f32x4){0.f, 0.f, 0.f, 0.f};

    float ar[16];
    short brh[16], brl[16];

    auto LOADA = [&](int k0) {
        #pragma unroll
        for (int j = 0; j < 16; ++j) {
            int kk = k0 + akh * 16 + j;
            float v;
            if (TA) v = Az[(long long)kk * 256 + m0 + arow];
            else    v = Az[(long long)(m0 + arow) * 256 + kk];
            if (!TA && cs) v *= cs[kk];
            ar[j] = v;
        }
    };
    auto LOADBB = [&](int k0) {
        #pragma unroll
        for (int j = 0; j < 16; ++j) {
            long long off = (long long)z * sB +
                            (long long)(k0 + akh * 16 + j) * 2048 + n0 + arow;
            brh[j] = Bh_[off];
            brl[j] = Bl_[off];
        }
    };
    auto WRITES = [&](short* buf) {
        #pragma unroll
        for (int ks = 0; ks < 2; ++ks) {
            float4 v0 = {ar[ks * 8 + 0], ar[ks * 8 + 1], ar[ks * 8 + 2], ar[ks * 8 + 3]};
            float4 v1 = {ar[ks * 8 + 4], ar[ks * 8 + 5], ar[ks * 8 + 6], ar[ks * 8 + 7]};
            short4 h0, l0, h1, l1;
            cvt4(v0, h0, l0);
            cvt4(v1, h1, l1);
            *(short8*)(buf + aws + ks * 128)        = pack8(h0, h1);
            *(short8*)(buf + 4096 + aws + ks * 128) = pack8(l0, l1);
        }
        #pragma unroll
        for (int ks = 0; ks < 2; ++ks) {
            short8 h, l;
            #pragma unroll
            for (int i = 0; i < 8; ++i) { h[i] = brh[ks * 8 + i]; l[i] = brl[ks * 8 + i]; }
            *(short8*)(buf + 8192  + bws + ks * 128) = h;
            *(short8*)(buf + 12288 + bws + ks * 128) = l;
        }
    };

    const int ab = (wm >> 4) * 512 + L * 8;
    const int bb = (wn >> 4) * 512 + L * 8;
    auto COMPUTE = [&](const short* buf) {
        const short* AhS = buf;
        const short* AlS = buf + 4096;
        const short* BhS = buf + 8192;
        const short* BlS = buf + 12288;
        short8 AF[4], ALF[4], BFr[4], BLF[4];
        #pragma unroll
        for (int t = 0; t < 4; ++t) {
            AF[t]  = *(const short8*)(AhS + ab + t * 512);
            ALF[t] = *(const short8*)(AlS + ab + t * 512);
            BFr[t] = *(const short8*)(BhS + bb + t * 512);
            BLF[t] = *(const short8*)(BlS + bb + t * 512);
        }
        #pragma unroll
        for (int ti = 0; ti < 4; ++ti)
            #pragma unroll
            for (int tj = 0; tj < 4; ++tj) {
                acc[ti][tj] = __builtin_amdgcn_mfma_f32_16x16x32_bf16(AF[ti],  BFr[tj], acc[ti][tj], 0, 0, 0);
                acc[ti][tj] = __builtin_amdgcn_mfma_f32_16x16x32_bf16(AF[ti],  BLF[tj], acc[ti][tj], 0, 0, 0);
                acc[ti][tj] = __builtin_amdgcn_mfma_f32_16x16x32_bf16(ALF[ti], BFr[tj], acc[ti][tj], 0, 0, 0);
            }
    };

    // K=256 -> 8 panels. Regs hold panel t; write lds[t&1]; barrier;
    // prefetch panel t+1 regs; compute lds[t&1]. Single barrier/panel:
    // iter-(t-2) reads of lds[t&1] drained by barrier t-1 (lgkmcnt in
    // __syncthreads), so the overwrite at iter t is safe.
    LOADA(0);
    LOADBB(0);
    #pragma unroll
    for (int t = 0; t < 8; ++t) {
        WRITES(lds[t & 1]);
        __syncthreads();
        if (t < 7) { LOADA((t + 1) * 32); LOADBB((t + 1) * 32); }
        COMPUTE(lds[t & 1]);
    }

    // ---- epilogue: C/D layout col = lane&15, row = (lane>>4)*4 + reg ----
    const int lcol = L & 15, lrow = (L >> 4) * 4;
    #pragma unroll
    for (int ti = 0; ti < 4; ++ti) {
        #pragma unroll
        for (int r = 0; r < 4; ++r) {
            int gr = m0 + wm + ti * 16 + lrow + r;
            long long base = (long long)z * sB + (long long)gr * 2048;
            #pragma unroll
            for (int tj = 0; tj < 4; ++tj) {
                int gcol = n0 + wn + tj * 16 + lcol;
                long long idx = base + gcol;
                float v = acc[ti][tj][r];
                if (ACC) v += bf2f(Ch[idx]) + bf2f(Cl[idx]);
                short hh, ll;
                split1(v, hh, ll);
                Ch[idx] = hh;
                Cl[idx] = ll;
            }
        }
    }
}

// ---------------- fp64-accumulate affinity GEMM ----------------
__global__ __launch_bounds__(256) void gemm_bt_f64(
    const float* __restrict__ A,
    const short* __restrict__ Bh_, const short* __restrict__ Bl_,
    float* __restrict__ C)
{
    __shared__ float As[16][65];
    __shared__ float Bs[16][65];

    const int K = 2048;
    int z = blockIdx.z;
    const float* Az = A + (long long)z * 524288;
    C += (long long)z * 65536;

    int n0 = blockIdx.x * 64;
    int m0 = blockIdx.y * 64;
    int tid = threadIdx.x;
    int tx = tid & 15;
    int ty = tid >> 4;

    double acc[4][4];
    #pragma unroll
    for (int i = 0; i < 4; ++i)
        #pragma unroll
        for (int j = 0; j < 4; ++j) acc[i][j] = 0.0;

    int r  = tid >> 2;
    int c4 = (tid & 3) * 4;

    for (int k0 = 0; k0 < K; k0 += 16) {
        {
            const float4 v = *(const float4*)(Az + (long long)(m0 + r) * K + k0 + c4);
            As[c4 + 0][r] = v.x; As[c4 + 1][r] = v.y;
            As[c4 + 2][r] = v.z; As[c4 + 3][r] = v.w;
        }
        {
            long long off = (long long)z * 524288 + (long long)(n0 + r) * K + k0 + c4;
            short4 h = *(const short4*)(Bh_ + off);
            short4 l = *(const short4*)(Bl_ + off);
            Bs[c4 + 0][r] = bf2f(h.x) + bf2f(l.x);
            Bs[c4 + 1][r] = bf2f(h.y) + bf2f(l.y);
            Bs[c4 + 2][r] = bf2f(h.z) + bf2f(l.z);
            Bs[c4 + 3][r] = bf2f(h.w) + bf2f(l.w);
        }
        __syncthreads();

        #pragma unroll
        for (int kk = 0; kk < 16; ++kk) {
            double a[4], b[4];
            #pragma unroll
            for (int i = 0; i < 4; ++i) a[i] = (double)As[kk][ty + 16 * i];
            #pragma unroll
            for (int j = 0; j < 4; ++j) b[j] = (double)Bs[kk][tx + 16 * j];
            #pragma unroll
            for (int i = 0; i < 4; ++i)
                #pragma unroll
                for (int j = 0; j < 4; ++j)
                    acc[i][j] = fma(a[i], b[j], acc[i][j]);
        }
        __syncthreads();
    }

    #pragma unroll
    for (int i = 0; i < 4; ++i) {
        int rowl = m0 + ty + 16 * i;
        #pragma unroll
        for (int j = 0; j < 4; ++j)
            C[(long long)rowl * 256 + n0 + tx + 16 * j] = (float)acc[i][j];
    }
}

// =====================================================================
// Fused Sinkhorn: one 1024-thread block per batch; S register-resident.
// =====================================================================
__global__ __launch_bounds__(1024, 4) void sk_fused(float* __restrict__ S,
                                                    const int* __restrict__ n1)
{
    __shared__ float pmax[16][256];
    __shared__ float psum[16][256];
    __shared__ float lseS[256];

    const int b = blockIdx.x;
    const int tid = threadIdx.x;
    const int w = tid >> 6, l = tid & 63;
    const int lim = n1[b];
    float* Sb = S + (long long)b * 65536;

    float4 v[16];
    #pragma unroll
    for (int r = 0; r < 16; ++r) {
        int n = w * 16 + r;
        if (n < lim) {
            float4 x = *(const float4*)(Sb + n * 256 + l * 4);
            v[r].x = x.x / SK_TAU; v[r].y = x.y / SK_TAU;
            v[r].z = x.z / SK_TAU; v[r].w = x.w / SK_TAU;
        } else {
            v[r] = (float4){NEGV, NEGV, NEGV, NEGV};
        }
    }

    for (int it = 0; it < 10; ++it) {
        if ((it & 1) == 0) {
            #pragma unroll
            for (int r = 0; r < 16; ++r) {
                if (w * 16 + r >= lim) continue;
                float m = fmaxf(fmaxf(v[r].x, v[r].y), fmaxf(v[r].z, v[r].w));
                #pragma unroll
                for (int off = 1; off < 64; off <<= 1) m = fmaxf(m, __shfl_xor(m, off));
                float s = expf(v[r].x - m) + expf(v[r].y - m) +
                          expf(v[r].z - m) + expf(v[r].w - m);
                #pragma unroll
                for (int off = 1; off < 64; off <<= 1) s += __shfl_xor(s, off);
                float lse = m + logf(s);
                v[r].x -= lse; v[r].y -= lse; v[r].z -= lse; v[r].w -= lse;
            }
        } else {
            float cm[4] = {-3.4e38f, -3.4e38f, -3.4e38f, -3.4e38f};
            #pragma unroll
            for (int r = 0; r < 16; ++r) {
                cm[0] = fmaxf(cm[0], v[r].x); cm[1] = fmaxf(cm[1], v[r].y);
                cm[2] = fmaxf(cm[2], v[r].z); cm[3] = fmaxf(cm[3], v[r].w);
            }
            float cs[4] = {0.f, 0.f, 0.f, 0.f};
            #pragma unroll
            for (int r = 0; r < 16; ++r) {
                cs[0] += expf(v[r].x - cm[0]); cs[1] += expf(v[r].y - cm[1]);
                cs[2] += expf(v[r].z - cm[2]); cs[3] += expf(v[r].w - cm[3]);
            }
            #pragma unroll
            for (int j = 0; j < 4; ++j) {
                pmax[w][l * 4 + j] = cm[j];
                psum[w][l * 4 + j] = cs[j];
            }
            __syncthreads();
            if (tid < 256) {
                float m = -3.4e38f, s = 0.f;
                #pragma unroll
                for (int ww = 0; ww < 16; ++ww) {
                    float pm = pmax[ww][tid], ps = psum[ww][tid];
                    float nm = fmaxf(m, pm);
                    s = s * expf(m - nm) + ps * expf(pm - nm);
                    m = nm;
                }
                lseS[tid] = m + logf(s);
            }
            __syncthreads();
            float l0 = lseS[l * 4 + 0], l1 = lseS[l * 4 + 1];
            float l2 = lseS[l * 4 + 2], l3 = lseS[l * 4 + 3];
            #pragma unroll
            for (int r = 0; r < 16; ++r) {
                if (w * 16 + r >= lim) continue;
                v[r].x -= l0; v[r].y -= l1; v[r].z -= l2; v[r].w -= l3;
            }
        }
    }

    #pragma unroll
    for (int r = 0; r < 16; ++r) {
        int n = w * 16 + r;
        float4 o;
        if (n < lim) {
            o.x = expf(v[r].x); o.y = expf(v[r].y);
            o.z = expf(v[r].z); o.w = expf(v[r].w);
        } else {
            o = (float4){0.f, 0.f, 0.f, 0.f};
        }
        *(float4*)(Sb + n * 256 + l * 4) = o;
    }
}

// ---------------- launch wrappers ----------------
static void gw(hipStream_t st, int om, const short* Ah, const short* Al, int lda,
               const float* Bf, int K,
               float* Cf, short* Ch, short* Cl, const float* bias, int relu)
{
    dim3 grid(16, 64), block(256);
    if (om == 0)
        gemm_w<0><<<grid, block, 0, st>>>(Ah, Al, Ah, Al, K, lda, Bf, K,
                                          Cf, nullptr, nullptr, bias, relu);
    else
        gemm_w<1><<<grid, block, 0, st>>>(Ah, Al, Ah, Al, K, lda, Bf, K,
                                          nullptr, Ch, Cl, bias, relu);
}

static void gwcat(hipStream_t st, const short* A1h, const short* A1l,
                  const short* A2h, const short* A2l,
                  const float* Bf, short* Ch, short* Cl, const float* bias)
{
    dim3 grid(16, 64), block(256);
    gemm_w<1><<<grid, block, 0, st>>>(A1h, A1l, A2h, A2l, 2048, 2048, Bf, 4096,
                                      nullptr, Ch, Cl, bias, 0);
}

// ---------------- driver ----------------
extern "C" void kernel_launch(void* const* d_in, const int* in_sizes, int n_in,
                              void* d_out, int out_size, void* d_ws, size_t ws_size,
                              hipStream_t stream)
{
    const float* feat1 = (const float*)d_in[0];
    const float* feat2 = (const float*)d_in[1];
    const float* A1    = (const float*)d_in[2];
    const float* A2    = (const float*)d_in[3];
    const int*   n1    = (const int*)d_in[4];
    const float* W0a = (const float*)d_in[8];  const float* b0a = (const float*)d_in[9];
    const float* W0u = (const float*)d_in[10]; const float* b0u = (const float*)d_in[11];
    const float* W1a = (const float*)d_in[12]; const float* b1a = (const float*)d_in[13];
    const float* W1u = (const float*)d_in[14]; const float* b1u = (const float*)d_in[15];
    const float* Wc  = (const float*)d_in[16]; const float* bc  = (const float*)d_in[17];
    const float* Aaff0 = (const float*)d_in[18];
    const float* Aaff1 = (const float*)d_in[19];

    const long long TSZ = 16777216LL;
    const long long PL  = 16777216LL;
    const long long PF  = 8388608LL;

    float* T1f = (float*)d_ws;
    float* T2f = T1f + TSZ;
    float* T3f = T2f + TSZ;
    float* T4f = T3f + TSZ;
    short *T1h = (short*)T1f, *T1l = T1h + PL;
    short *T2h = (short*)T2f, *T2l = T2h + PL;
    short *T3h = (short*)T3f, *T3l = T3h + PL;
    short *T4h = (short*)T4f, *T4l = T4h + PL;

    short* f1h = (short*)T4f;      short* f1l = f1h + PF;
    short* f2h = f1h + 2 * PF;     short* f2l = f1h + 3 * PF;
    float* invA = (float*)T4f;     // overlaps f1h rows: written only after
    float* invB = invA + 8192;     // the last f1 read (ordering below)

    float* S    = (float*)d_out;
    float* inv1 = S;
    float* inv2 = S + 8192;

    dim3 bgrid(16, 2, 32), bblk(256);

    // ===== Phase 0: split feats =====
    split_mat<<<2048, 256, 0, stream>>>(feat1, f1h, f1l, 8192LL * 1024 / 4);
    split_mat<<<2048, 256, 0, stream>>>(feat2, f2h, f2l, 8192LL * 1024 / 4);

    // ===== Phase 1: gconv layer 0 (K=1024, lda=1024) =====
    gw(stream, 1, f1h, f1l, 1024, W0u, 1024, nullptr, T1h, T1l, b0u, 1);
    gw(stream, 1, f2h, f2l, 1024, W0u, 1024, nullptr, T2h, T2l, b0u, 1);
    gw(stream, 1, f1h, f1l, 1024, W0a, 1024, nullptr, T3h, T3l, b0a, 1);   // last f1 read
    colnorm_k<<<32, 256, 0, stream>>>(A1, invA);
    colnorm_k<<<32, 256, 0, stream>>>(A2, invB);
    bgemm_m<false, true><<<bgrid, bblk, 0, stream>>>(A1, T3h, T3l, T1h, T1l, invA);
    gw(stream, 1, f2h, f2l, 1024, W0a, 1024, nullptr, T3h, T3l, b0a, 1);
    bgemm_m<false, true><<<bgrid, bblk, 0, stream>>>(A2, T3h, T3l, T2h, T2l, invB);

    // ===== Phase 2: affinity 0 =====
    gw(stream, 0, T1h, T1l, 2048, Aaff0, 2048, T3f, nullptr, nullptr, nullptr, 0);
    gemm_bt_f64<<<dim3(4, 4, 32), 256, 0, stream>>>(T3f, T2h, T2l, S);

    sk_fused<<<32, 1024, 0, stream>>>(S, n1);

    // ===== Phase 4: cross-graph update =====
    bgemm_m<false, false><<<bgrid, bblk, 0, stream>>>(S, T2h, T2l, T3h, T3l, nullptr); // c1 = S @ emb2
    gwcat(stream, T1h, T1l, T3h, T3l, Wc, T4h, T4l, bc);   // new1 = [emb1|c1]@Wc+bc
    bgemm_m<true, false><<<bgrid, bblk, 0, stream>>>(S, T1h, T1l, T3h, T3l, nullptr);  // c2 = S^T @ emb1
    gwcat(stream, T2h, T2l, T3h, T3l, Wc, T1h, T1l, bc);   // new2 = [emb2|c2]@Wc+bc

    // ===== Phase 5: gconv layer 1 (K=2048, lda=2048) =====
    gw(stream, 1, T4h, T4l, 2048, W1a, 2048, nullptr, T2h, T2l, b1a, 1);   // a-path g1
    gw(stream, 1, T4h, T4l, 2048, W1u, 2048, nullptr, T3h, T3l, b1u, 1);   // u-path g1
    colnorm_k<<<32, 256, 0, stream>>>(A1, inv1);
    bgemm_m<false, true><<<bgrid, bblk, 0, stream>>>(A1, T2h, T2l, T3h, T3l, inv1);    // emb1' = T3
    gw(stream, 1, T1h, T1l, 2048, W1a, 2048, nullptr, T2h, T2l, b1a, 1);   // a-path g2
    gw(stream, 1, T1h, T1l, 2048, W1u, 2048, nullptr, T4h, T4l, b1u, 1);   // u-path g2
    colnorm_k<<<32, 256, 0, stream>>>(A2, inv2);
    bgemm_m<false, true><<<bgrid, bblk, 0, stream>>>(A2, T2h, T2l, T4h, T4l, inv2);    // emb2' = T4

    // ===== Phase 6: affinity 1 =====
    gw(stream, 0, T3h, T3l, 2048, Aaff1, 2048, T1f, nullptr, nullptr, nullptr, 0);
    gemm_bt_f64<<<dim3(4, 4, 32), 256, 0, stream>>>(T1f, T4h, T4l, S);

    sk_fused<<<32, 1024, 0, stream>>>(S, n1);
}

// Round 7
// 4275.847 us; speedup vs baseline: 1.2066x; 1.0149x over previous
//
#include <hip/hip_runtime.h>
#include <math.h>

#define NEGV -1e9f
#define SK_TAU 0.05f

typedef __attribute__((ext_vector_type(4))) float f32x4;
typedef __attribute__((ext_vector_type(8))) short short8;

#define GLDS(g, l) __builtin_amdgcn_global_load_lds( \
    (const __attribute__((address_space(1))) void*)(g), \
    (__attribute__((address_space(3))) void*)(l), 16, 0, 0)

// ---------------- bf16 split helpers ----------------
__device__ inline unsigned bf16rtn(float x) {
    unsigned u = __float_as_uint(x);
    return (u + 0x7FFFu + ((u >> 16) & 1u)) >> 16;
}
__device__ inline float bf2f(short h) {
    return __uint_as_float(((unsigned)(unsigned short)h) << 16);
}
__device__ inline void split1(float x, short& h, short& l) {
    unsigned hu = bf16rtn(x);
    h = (short)hu;
    float r = x - __uint_as_float(hu << 16);
    l = (short)(__float_as_uint(r) >> 16);
}
__device__ inline void cvt4(const float4 v, short4& h, short4& l) {
    unsigned h0 = bf16rtn(v.x), h1 = bf16rtn(v.y), h2 = bf16rtn(v.z), h3 = bf16rtn(v.w);
    h.x = (short)h0; h.y = (short)h1; h.z = (short)h2; h.w = (short)h3;
    float l0 = v.x - __uint_as_float(h0 << 16);
    float l1 = v.y - __uint_as_float(h1 << 16);
    float l2 = v.z - __uint_as_float(h2 << 16);
    float l3 = v.w - __uint_as_float(h3 << 16);
    l.x = (short)(__float_as_uint(l0) >> 16);
    l.y = (short)(__float_as_uint(l1) >> 16);
    l.z = (short)(__float_as_uint(l2) >> 16);
    l.w = (short)(__float_as_uint(l3) >> 16);
}
__device__ inline short8 pack8(const short4 a, const short4 b) {
    short8 r;
    r[0] = a.x; r[1] = a.y; r[2] = a.z; r[3] = a.w;
    r[4] = b.x; r[5] = b.y; r[6] = b.z; r[7] = b.w;
    return r;
}

// ---------------- inv column L1 norm ----------------
__global__ __launch_bounds__(256) void colnorm_k(const float* __restrict__ A,
                                                 float* __restrict__ inv)
{
    int idx = blockIdx.x * 256 + threadIdx.x;
    int b = idx >> 8, m = idx & 255;
    const float* p = A + (long long)b * 65536 + m;
    float s = 0.f;
    #pragma unroll 8
    for (int n = 0; n < 256; ++n) s += fabsf(p[n * 256]);
    inv[idx] = 1.f / fmaxf(s, 1e-12f);
}

// ---------------- fp32 -> split planes ----------------
__global__ __launch_bounds__(256) void split_mat(const float* __restrict__ X,
                                                 short* __restrict__ H,
                                                 short* __restrict__ L, long long n4)
{
    long long i = (long long)blockIdx.x * 256 + threadIdx.x;
    long long stride = (long long)gridDim.x * 256;
    for (; i < n4; i += stride) {
        float4 v = ((const float4*)X)[i];
        short4 h, l;
        cvt4(v, h, l);
        ((short4*)H)[i] = h;
        ((short4*)L)[i] = l;
    }
}

// =====================================================================
// 8-wave 256x256-tile 4-phase split-bf16 GEMM engine:
//   C = epi( [A1 | A2] @ Bf + bias ),  OM 0 = fp32 store, 1 = split store.
// 512 threads (8 waves, wave tile 128x64), BK=32, 128 KB dynamic LDS
// double buffer: per buf [Ah 8192 | Al 8192 | Bh 8192 | Bl 8192] shorts,
// chunked (16 rows x 32 k = 512 shorts per chunk, conflict-free reads).
// Per panel: 4 phases, each {ds_read quadrant frags; staging slice;
// s_barrier; lgkmcnt(0)+sched_barrier; setprio(1); 24 MFMA; setprio(0);
// s_barrier}. vmcnt drained ONCE per panel (boundary) so global_load_lds
// stays in flight across phase barriers (T3/T4); setprio arbitrates the
// role-split waves (T5). MFMA accumulation order per element identical
// to the previous engine -> identical numerics.
// =====================================================================
template <int OM>
__global__ __launch_bounds__(512, 2) void gemm_w8(
    const short* __restrict__ A1h, const short* __restrict__ A1l,
    const short* __restrict__ A2h, const short* __restrict__ A2l,
    int K1, int lda,
    const float* __restrict__ Bf, int K,
    float* __restrict__ Cf, short* __restrict__ Ch, short* __restrict__ Cl,
    const float* __restrict__ bias, int relu)
{
    extern __shared__ short lds_s[];    // 2 x 32768 shorts = 128 KB

    const int tid = threadIdx.x;
    const int wave = tid >> 6, L = tid & 63;
    const int m0 = blockIdx.y * 256, n0 = blockIdx.x * 256;
    const int wm = (wave & 1) * 128, wn = (wave >> 1) * 64;
    const int lm = L & 15, lh = (L >> 4) * 8;
    const int c0 = wave * 2;            // A chunks owned for staging

    long long grow[2];
    #pragma unroll
    for (int c = 0; c < 2; ++c)
        grow[c] = (long long)(m0 + (c0 + c) * 16 + lm) * lda + lh;

    // B staging: thread owns (col, k-half16)
    const int bcol = tid & 255, bkh = tid >> 8;
    const float* bp = Bf + (long long)(bkh * 16) * 2048 + n0 + bcol;
    const int bws = (bcol >> 4) * 512 + (bcol & 15) * 8 + bkh * 256;

    f32x4 acc[8][4];
    #pragma unroll
    for (int i = 0; i < 8; ++i)
        #pragma unroll
        for (int j = 0; j < 4; ++j)
            acc[i][j] = (f32x4){0.f, 0.f, 0.f, 0.f};

    float brA[16];
    short8 AF[4], ALF[4], BFr[4], BLF[4];
    const int abase = (wm >> 4) * 512 + L * 8;   // 0 or 8*512
    const int bbase = (wn >> 4) * 512 + L * 8;   // {0,4,8,12}*512

    auto GLDS_A = [&](short* buf, int k0, int plane) {
        const short* s; int ko;
        if (k0 < K1) { s = plane ? A1l : A1h; ko = k0; }
        else         { s = plane ? A2l : A2h; ko = k0 - K1; }
        #pragma unroll
        for (int c = 0; c < 2; ++c)
            GLDS(s + grow[c] + ko, buf + plane * 8192 + (c0 + c) * 512);
    };
    auto LOADB = [&](int k0) {
        #pragma unroll
        for (int j = 0; j < 16; ++j)
            brA[j] = bp[((long long)k0 + j) * 2048];
    };
    auto WRITEB = [&](short* buf) {
        #pragma unroll
        for (int ks = 0; ks < 2; ++ks) {
            float4 v0 = {brA[ks * 8 + 0], brA[ks * 8 + 1], brA[ks * 8 + 2], brA[ks * 8 + 3]};
            float4 v1 = {brA[ks * 8 + 4], brA[ks * 8 + 5], brA[ks * 8 + 6], brA[ks * 8 + 7]};
            short4 h0, l0, h1, l1;
            cvt4(v0, h0, l0);
            cvt4(v1, h1, l1);
            *(short8*)(buf + 16384 + bws + ks * 128) = pack8(h0, h1);
            *(short8*)(buf + 24576 + bws + ks * 128) = pack8(l0, l1);
        }
    };

#define RD_A8(H) do { _Pragma("unroll") for (int i_ = 0; i_ < 4; ++i_) { \
        AF[i_]  = *(const short8*)(cur + abase + ((H) * 4 + i_) * 512); \
        ALF[i_] = *(const short8*)(cur + 8192 + abase + ((H) * 4 + i_) * 512); } } while (0)

#define RD_B8(NH) do { _Pragma("unroll") for (int j_ = 0; j_ < 2; ++j_) { \
        BFr[(NH) * 2 + j_] = *(const short8*)(cur + 16384 + bbase + ((NH) * 2 + j_) * 512); \
        BLF[(NH) * 2 + j_] = *(const short8*)(cur + 24576 + bbase + ((NH) * 2 + j_) * 512); } } while (0)

#define MQ8(MH, NH) do { _Pragma("unroll") for (int i_ = 0; i_ < 4; ++i_) \
        _Pragma("unroll") for (int j_ = 0; j_ < 2; ++j_) { \
            acc[(MH)*4+i_][(NH)*2+j_] = __builtin_amdgcn_mfma_f32_16x16x32_bf16(AF[i_],  BFr[(NH)*2+j_], acc[(MH)*4+i_][(NH)*2+j_], 0, 0, 0); \
            acc[(MH)*4+i_][(NH)*2+j_] = __builtin_amdgcn_mfma_f32_16x16x32_bf16(AF[i_],  BLF[(NH)*2+j_], acc[(MH)*4+i_][(NH)*2+j_], 0, 0, 0); \
            acc[(MH)*4+i_][(NH)*2+j_] = __builtin_amdgcn_mfma_f32_16x16x32_bf16(ALF[i_], BFr[(NH)*2+j_], acc[(MH)*4+i_][(NH)*2+j_], 0, 0, 0); } } while (0)

#define PH_IN() do { __builtin_amdgcn_s_barrier(); \
        asm volatile("s_waitcnt lgkmcnt(0)" ::: "memory"); \
        __builtin_amdgcn_sched_barrier(0); \
        __builtin_amdgcn_s_setprio(1); } while (0)
#define PH_OUT() do { __builtin_amdgcn_s_setprio(0); \
        __builtin_amdgcn_s_barrier(); } while (0)

    const int NT = K >> 5;

    // ---- prologue: panel 0 -> buf0, full drain once ----
    LOADB(0);
    GLDS_A(lds_s, 0, 0);
    GLDS_A(lds_s, 0, 1);
    WRITEB(lds_s);
    __syncthreads();

    for (int t = 0; t < NT; ++t) {
        short* cur = lds_s + (t & 1) * 32768;
        short* nxt = lds_s + ((t + 1) & 1) * 32768;
        const bool more = (t + 1) < NT;
        const int kn = (t + 1) << 5;

        // ph0: A-half0 + B-half0 frags; issue next-panel B loads + Ah DMA
        RD_A8(0); RD_B8(0);
        if (more) { LOADB(kn); GLDS_A(nxt, kn, 0); }
        PH_IN(); MQ8(0, 0); PH_OUT();

        // ph1: B-half1 frags; issue next-panel Al DMA
        RD_B8(1);
        if (more) GLDS_A(nxt, kn, 1);
        PH_IN(); MQ8(0, 1); PH_OUT();

        // ph2: A-half1 frags; convert+write next-panel B to LDS
        RD_A8(1);
        if (more) WRITEB(nxt);
        PH_IN(); MQ8(1, 0); PH_OUT();

        // ph3: pure MFMA; panel boundary drains vmcnt once
        __builtin_amdgcn_s_setprio(1);
        MQ8(1, 1);
        __builtin_amdgcn_s_setprio(0);
        asm volatile("s_waitcnt vmcnt(0)" ::: "memory");
        __builtin_amdgcn_s_barrier();
    }

#undef RD_A8
#undef RD_B8
#undef MQ8
#undef PH_IN
#undef PH_OUT

    // ---- epilogue: C/D layout col = lane&15, row = (lane>>4)*4 + reg ----
    const int lcol = L & 15, lrow = (L >> 4) * 4;
    float bv[4];
    #pragma unroll
    for (int tj = 0; tj < 4; ++tj)
        bv[tj] = bias ? bias[n0 + wn + tj * 16 + lcol] : 0.f;

    #pragma unroll
    for (int ti = 0; ti < 8; ++ti) {
        #pragma unroll
        for (int r = 0; r < 4; ++r) {
            int gr = m0 + wm + ti * 16 + lrow + r;
            #pragma unroll
            for (int tj = 0; tj < 4; ++tj) {
                int gcol = n0 + wn + tj * 16 + lcol;
                float v = acc[ti][tj][r] + bv[tj];
                if (relu) v = fmaxf(v, 0.f);
                long long idx = (long long)gr * 2048 + gcol;
                if (OM == 0) {
                    Cf[idx] = v;
                } else {
                    short hh, ll;
                    split1(v, hh, ll);
                    Ch[idx] = hh;
                    Cl[idx] = ll;
                }
            }
        }
    }
}

// =====================================================================
// Batched MFMA GEMM (proven round-6 engine, unchanged):
//   per batch z: C[256][2048] = A(256x256 fp32, opt colscale) @ B(split)
// =====================================================================
template <bool TA, bool ACC>
__global__ __launch_bounds__(256, 2) void bgemm_m(
    const float* __restrict__ A,
    const short* __restrict__ Bh_, const short* __restrict__ Bl_,
    short* __restrict__ Ch, short* __restrict__ Cl,
    const float* __restrict__ colscale)
{
    __shared__ alignas(16) short lds[2][16384];

    const int tid = threadIdx.x;
    const int wave = tid >> 6, L = tid & 63;
    const int z = blockIdx.z;
    const int n0 = blockIdx.x * 128, m0 = blockIdx.y * 128;
    const int wm = (wave & 1) * 64, wn = (wave >> 1) * 64;
    const long long sB = 524288;
    const float* Az = A + (long long)z * 65536;
    const float* cs = colscale ? colscale + z * 256 : nullptr;

    const int arow = tid & 127, akh = tid >> 7;
    const int aws = (arow >> 4) * 512 + (arow & 15) * 8 + akh * 256;
    const int bws = aws;

    f32x4 acc[4][4];
    #pragma unroll
    for (int i = 0; i < 4; ++i)
        #pragma unroll
        for (int j = 0; j < 4; ++j)
            acc[i][j] = (f32x4){0.f, 0.f, 0.f, 0.f};

    float ar[16];
    short brh[16], brl[16];

    auto LOADA = [&](int k0) {
        #pragma unroll
        for (int j = 0; j < 16; ++j) {
            int kk = k0 + akh * 16 + j;
            float v;
            if (TA) v = Az[(long long)kk * 256 + m0 + arow];
            else    v = Az[(long long)(m0 + arow) * 256 + kk];
            if (!TA && cs) v *= cs[kk];
            ar[j] = v;
        }
    };
    auto LOADBB = [&](int k0) {
        #pragma unroll
        for (int j = 0; j < 16; ++j) {
            long long off = (long long)z * sB +
                            (long long)(k0 + akh * 16 + j) * 2048 + n0 + arow;
            brh[j] = Bh_[off];
            brl[j] = Bl_[off];
        }
    };
    auto WRITES = [&](short* buf) {
        #pragma unroll
        for (int ks = 0; ks < 2; ++ks) {
            float4 v0 = {ar[ks * 8 + 0], ar[ks * 8 + 1], ar[ks * 8 + 2], ar[ks * 8 + 3]};
            float4 v1 = {ar[ks * 8 + 4], ar[ks * 8 + 5], ar[ks * 8 + 6], ar[ks * 8 + 7]};
            short4 h0, l0, h1, l1;
            cvt4(v0, h0, l0);
            cvt4(v1, h1, l1);
            *(short8*)(buf + aws + ks * 128)        = pack8(h0, h1);
            *(short8*)(buf + 4096 + aws + ks * 128) = pack8(l0, l1);
        }
        #pragma unroll
        for (int ks = 0; ks < 2; ++ks) {
            short8 h, l;
            #pragma unroll
            for (int i = 0; i < 8; ++i) { h[i] = brh[ks * 8 + i]; l[i] = brl[ks * 8 + i]; }
            *(short8*)(buf + 8192  + bws + ks * 128) = h;
            *(short8*)(buf + 12288 + bws + ks * 128) = l;
        }
    };

    const int ab = (wm >> 4) * 512 + L * 8;
    const int bb = (wn >> 4) * 512 + L * 8;
    auto COMPUTE = [&](const short* buf) {
        const short* AhS = buf;
        const short* AlS = buf + 4096;
        const short* BhS = buf + 8192;
        const short* BlS = buf + 12288;
        short8 AF[4], ALF[4], BFr[4], BLF[4];
        #pragma unroll
        for (int t = 0; t < 4; ++t) {
            AF[t]  = *(const short8*)(AhS + ab + t * 512);
            ALF[t] = *(const short8*)(AlS + ab + t * 512);
            BFr[t] = *(const short8*)(BhS + bb + t * 512);
            BLF[t] = *(const short8*)(BlS + bb + t * 512);
        }
        #pragma unroll
        for (int ti = 0; ti < 4; ++ti)
            #pragma unroll
            for (int tj = 0; tj < 4; ++tj) {
                acc[ti][tj] = __builtin_amdgcn_mfma_f32_16x16x32_bf16(AF[ti],  BFr[tj], acc[ti][tj], 0, 0, 0);
                acc[ti][tj] = __builtin_amdgcn_mfma_f32_16x16x32_bf16(AF[ti],  BLF[tj], acc[ti][tj], 0, 0, 0);
                acc[ti][tj] = __builtin_amdgcn_mfma_f32_16x16x32_bf16(ALF[ti], BFr[tj], acc[ti][tj], 0, 0, 0);
            }
    };

    LOADA(0);
    LOADBB(0);
    #pragma unroll
    for (int t = 0; t < 8; ++t) {
        WRITES(lds[t & 1]);
        __syncthreads();
        if (t < 7) { LOADA((t + 1) * 32); LOADBB((t + 1) * 32); }
        COMPUTE(lds[t & 1]);
    }

    const int lcol = L & 15, lrow = (L >> 4) * 4;
    #pragma unroll
    for (int ti = 0; ti < 4; ++ti) {
        #pragma unroll
        for (int r = 0; r < 4; ++r) {
            int gr = m0 + wm + ti * 16 + lrow + r;
            long long base = (long long)z * sB + (long long)gr * 2048;
            #pragma unroll
            for (int tj = 0; tj < 4; ++tj) {
                int gcol = n0 + wn + tj * 16 + lcol;
                long long idx = base + gcol;
                float v = acc[ti][tj][r];
                if (ACC) v += bf2f(Ch[idx]) + bf2f(Cl[idx]);
                short hh, ll;
                split1(v, hh, ll);
                Ch[idx] = hh;
                Cl[idx] = ll;
            }
        }
    }
}

// ---------------- fp64-accumulate affinity GEMM ----------------
__global__ __launch_bounds__(256) void gemm_bt_f64(
    const float* __restrict__ A,
    const short* __restrict__ Bh_, const short* __restrict__ Bl_,
    float* __restrict__ C)
{
    __shared__ float As[16][65];
    __shared__ float Bs[16][65];

    const int K = 2048;
    int z = blockIdx.z;
    const float* Az = A + (long long)z * 524288;
    C += (long long)z * 65536;

    int n0 = blockIdx.x * 64;
    int m0 = blockIdx.y * 64;
    int tid = threadIdx.x;
    int tx = tid & 15;
    int ty = tid >> 4;

    double acc[4][4];
    #pragma unroll
    for (int i = 0; i < 4; ++i)
        #pragma unroll
        for (int j = 0; j < 4; ++j) acc[i][j] = 0.0;

    int r  = tid >> 2;
    int c4 = (tid & 3) * 4;

    for (int k0 = 0; k0 < K; k0 += 16) {
        {
            const float4 v = *(const float4*)(Az + (long long)(m0 + r) * K + k0 + c4);
            As[c4 + 0][r] = v.x; As[c4 + 1][r] = v.y;
            As[c4 + 2][r] = v.z; As[c4 + 3][r] = v.w;
        }
        {
            long long off = (long long)z * 524288 + (long long)(n0 + r) * K + k0 + c4;
            short4 h = *(const short4*)(Bh_ + off);
            short4 l = *(const short4*)(Bl_ + off);
            Bs[c4 + 0][r] = bf2f(h.x) + bf2f(l.x);
            Bs[c4 + 1][r] = bf2f(h.y) + bf2f(l.y);
            Bs[c4 + 2][r] = bf2f(h.z) + bf2f(l.z);
            Bs[c4 + 3][r] = bf2f(h.w) + bf2f(l.w);
        }
        __syncthreads();

        #pragma unroll
        for (int kk = 0; kk < 16; ++kk) {
            double a[4], b[4];
            #pragma unroll
            for (int i = 0; i < 4; ++i) a[i] = (double)As[kk][ty + 16 * i];
            #pragma unroll
            for (int j = 0; j < 4; ++j) b[j] = (double)Bs[kk][tx + 16 * j];
            #pragma unroll
            for (int i = 0; i < 4; ++i)
                #pragma unroll
                for (int j = 0; j < 4; ++j)
                    acc[i][j] = fma(a[i], b[j], acc[i][j]);
        }
        __syncthreads();
    }

    #pragma unroll
    for (int i = 0; i < 4; ++i) {
        int rowl = m0 + ty + 16 * i;
        #pragma unroll
        for (int j = 0; j < 4; ++j)
            C[(long long)rowl * 256 + n0 + tx + 16 * j] = (float)acc[i][j];
    }
}

// =====================================================================
// Fused Sinkhorn: one 1024-thread block per batch; S register-resident.
// =====================================================================
__global__ __launch_bounds__(1024, 4) void sk_fused(float* __restrict__ S,
                                                    const int* __restrict__ n1)
{
    __shared__ float pmax[16][256];
    __shared__ float psum[16][256];
    __shared__ float lseS[256];

    const int b = blockIdx.x;
    const int tid = threadIdx.x;
    const int w = tid >> 6, l = tid & 63;
    const int lim = n1[b];
    float* Sb = S + (long long)b * 65536;

    float4 v[16];
    #pragma unroll
    for (int r = 0; r < 16; ++r) {
        int n = w * 16 + r;
        if (n < lim) {
            float4 x = *(const float4*)(Sb + n * 256 + l * 4);
            v[r].x = x.x / SK_TAU; v[r].y = x.y / SK_TAU;
            v[r].z = x.z / SK_TAU; v[r].w = x.w / SK_TAU;
        } else {
            v[r] = (float4){NEGV, NEGV, NEGV, NEGV};
        }
    }

    for (int it = 0; it < 10; ++it) {
        if ((it & 1) == 0) {
            #pragma unroll
            for (int r = 0; r < 16; ++r) {
                if (w * 16 + r >= lim) continue;
                float m = fmaxf(fmaxf(v[r].x, v[r].y), fmaxf(v[r].z, v[r].w));
                #pragma unroll
                for (int off = 1; off < 64; off <<= 1) m = fmaxf(m, __shfl_xor(m, off));
                float s = expf(v[r].x - m) + expf(v[r].y - m) +
                          expf(v[r].z - m) + expf(v[r].w - m);
                #pragma unroll
                for (int off = 1; off < 64; off <<= 1) s += __shfl_xor(s, off);
                float lse = m + logf(s);
                v[r].x -= lse; v[r].y -= lse; v[r].z -= lse; v[r].w -= lse;
            }
        } else {
            float cm[4] = {-3.4e38f, -3.4e38f, -3.4e38f, -3.4e38f};
            #pragma unroll
            for (int r = 0; r < 16; ++r) {
                cm[0] = fmaxf(cm[0], v[r].x); cm[1] = fmaxf(cm[1], v[r].y);
                cm[2] = fmaxf(cm[2], v[r].z); cm[3] = fmaxf(cm[3], v[r].w);
            }
            float cs[4] = {0.f, 0.f, 0.f, 0.f};
            #pragma unroll
            for (int r = 0; r < 16; ++r) {
                cs[0] += expf(v[r].x - cm[0]); cs[1] += expf(v[r].y - cm[1]);
                cs[2] += expf(v[r].z - cm[2]); cs[3] += expf(v[r].w - cm[3]);
            }
            #pragma unroll
            for (int j = 0; j < 4; ++j) {
                pmax[w][l * 4 + j] = cm[j];
                psum[w][l * 4 + j] = cs[j];
            }
            __syncthreads();
            if (tid < 256) {
                float m = -3.4e38f, s = 0.f;
                #pragma unroll
                for (int ww = 0; ww < 16; ++ww) {
                    float pm = pmax[ww][tid], ps = psum[ww][tid];
                    float nm = fmaxf(m, pm);
                    s = s * expf(m - nm) + ps * expf(pm - nm);
                    m = nm;
                }
                lseS[tid] = m + logf(s);
            }
            __syncthreads();
            float l0 = lseS[l * 4 + 0], l1 = lseS[l * 4 + 1];
            float l2 = lseS[l * 4 + 2], l3 = lseS[l * 4 + 3];
            #pragma unroll
            for (int r = 0; r < 16; ++r) {
                if (w * 16 + r >= lim) continue;
                v[r].x -= l0; v[r].y -= l1; v[r].z -= l2; v[r].w -= l3;
            }
        }
    }

    #pragma unroll
    for (int r = 0; r < 16; ++r) {
        int n = w * 16 + r;
        float4 o;
        if (n < lim) {
            o.x = expf(v[r].x); o.y = expf(v[r].y);
            o.z = expf(v[r].z); o.w = expf(v[r].w);
        } else {
            o = (float4){0.f, 0.f, 0.f, 0.f};
        }
        *(float4*)(Sb + n * 256 + l * 4) = o;
    }
}

// ---------------- launch wrappers ----------------
static void set_lds_attr() {
    static bool done = false;
    if (done) return;
    hipFuncSetAttribute((const void*)gemm_w8<0>,
                        hipFuncAttributeMaxDynamicSharedMemorySize, 131072);
    hipFuncSetAttribute((const void*)gemm_w8<1>,
                        hipFuncAttributeMaxDynamicSharedMemorySize, 131072);
    done = true;
}

static void gw(hipStream_t st, int om, const short* Ah, const short* Al, int lda,
               const float* Bf, int K,
               float* Cf, short* Ch, short* Cl, const float* bias, int relu)
{
    set_lds_attr();
    dim3 grid(8, 32), block(512);
    if (om == 0)
        gemm_w8<0><<<grid, block, 131072, st>>>(Ah, Al, Ah, Al, K, lda, Bf, K,
                                                Cf, nullptr, nullptr, bias, relu);
    else
        gemm_w8<1><<<grid, block, 131072, st>>>(Ah, Al, Ah, Al, K, lda, Bf, K,
                                                nullptr, Ch, Cl, bias, relu);
}

static void gwcat(hipStream_t st, const short* A1h, const short* A1l,
                  const short* A2h, const short* A2l,
                  const float* Bf, short* Ch, short* Cl, const float* bias)
{
    set_lds_attr();
    dim3 grid(8, 32), block(512);
    gemm_w8<1><<<grid, block, 131072, st>>>(A1h, A1l, A2h, A2l, 2048, 2048, Bf, 4096,
                                            nullptr, Ch, Cl, bias, 0);
}

// ---------------- driver ----------------
extern "C" void kernel_launch(void* const* d_in, const int* in_sizes, int n_in,
                              void* d_out, int out_size, void* d_ws, size_t ws_size,
                              hipStream_t stream)
{
    const float* feat1 = (const float*)d_in[0];
    const float* feat2 = (const float*)d_in[1];
    const float* A1    = (const float*)d_in[2];
    const float* A2    = (const float*)d_in[3];
    const int*   n1    = (const int*)d_in[4];
    const float* W0a = (const float*)d_in[8];  const float* b0a = (const float*)d_in[9];
    const float* W0u = (const float*)d_in[10]; const float* b0u = (const float*)d_in[11];
    const float* W1a = (const float*)d_in[12]; const float* b1a = (const float*)d_in[13];
    const float* W1u = (const float*)d_in[14]; const float* b1u = (const float*)d_in[15];
    const float* Wc  = (const float*)d_in[16]; const float* bc  = (const float*)d_in[17];
    const float* Aaff0 = (const float*)d_in[18];
    const float* Aaff1 = (const float*)d_in[19];

    const long long TSZ = 16777216LL;
    const long long PL  = 16777216LL;
    const long long PF  = 8388608LL;

    float* T1f = (float*)d_ws;
    float* T2f = T1f + TSZ;
    float* T3f = T2f + TSZ;
    float* T4f = T3f + TSZ;
    short *T1h = (short*)T1f, *T1l = T1h + PL;
    short *T2h = (short*)T2f, *T2l = T2h + PL;
    short *T3h = (short*)T3f, *T3l = T3h + PL;
    short *T4h = (short*)T4f, *T4l = T4h + PL;

    short* f1h = (short*)T4f;      short* f1l = f1h + PF;
    short* f2h = f1h + 2 * PF;     short* f2l = f1h + 3 * PF;
    float* invA = (float*)T4f;     // overlaps f1h rows: written only after
    float* invB = invA + 8192;     // the last f1 read (ordering below)

    float* S    = (float*)d_out;
    float* inv1 = S;
    float* inv2 = S + 8192;

    dim3 bgrid(16, 2, 32), bblk(256);

    // ===== Phase 0: split feats =====
    split_mat<<<2048, 256, 0, stream>>>(feat1, f1h, f1l, 8192LL * 1024 / 4);
    split_mat<<<2048, 256, 0, stream>>>(feat2, f2h, f2l, 8192LL * 1024 / 4);

    // ===== Phase 1: gconv layer 0 (K=1024, lda=1024) =====
    gw(stream, 1, f1h, f1l, 1024, W0u, 1024, nullptr, T1h, T1l, b0u, 1);
    gw(stream, 1, f2h, f2l, 1024, W0u, 1024, nullptr, T2h, T2l, b0u, 1);
    gw(stream, 1, f1h, f1l, 1024, W0a, 1024, nullptr, T3h, T3l, b0a, 1);   // last f1 read
    colnorm_k<<<32, 256, 0, stream>>>(A1, invA);
    colnorm_k<<<32, 256, 0, stream>>>(A2, invB);
    bgemm_m<false, true><<<bgrid, bblk, 0, stream>>>(A1, T3h, T3l, T1h, T1l, invA);
    gw(stream, 1, f2h, f2l, 1024, W0a, 1024, nullptr, T3h, T3l, b0a, 1);
    bgemm_m<false, true><<<bgrid, bblk, 0, stream>>>(A2, T3h, T3l, T2h, T2l, invB);

    // ===== Phase 2: affinity 0 =====
    gw(stream, 0, T1h, T1l, 2048, Aaff0, 2048, T3f, nullptr, nullptr, nullptr, 0);
    gemm_bt_f64<<<dim3(4, 4, 32), 256, 0, stream>>>(T3f, T2h, T2l, S);

    sk_fused<<<32, 1024, 0, stream>>>(S, n1);

    // ===== Phase 4: cross-graph update =====
    bgemm_m<false, false><<<bgrid, bblk, 0, stream>>>(S, T2h, T2l, T3h, T3l, nullptr); // c1 = S @ emb2
    gwcat(stream, T1h, T1l, T3h, T3l, Wc, T4h, T4l, bc);   // new1 = [emb1|c1]@Wc+bc
    bgemm_m<true, false><<<bgrid, bblk, 0, stream>>>(S, T1h, T1l, T3h, T3l, nullptr);  // c2 = S^T @ emb1
    gwcat(stream, T2h, T2l, T3h, T3l, Wc, T1h, T1l, bc);   // new2 = [emb2|c2]@Wc+bc

    // ===== Phase 5: gconv layer 1 (K=2048, lda=2048) =====
    gw(stream, 1, T4h, T4l, 2048, W1a, 2048, nullptr, T2h, T2l, b1a, 1);   // a-path g1
    gw(stream, 1, T4h, T4l, 2048, W1u, 2048, nullptr, T3h, T3l, b1u, 1);   // u-path g1
    colnorm_k<<<32, 256, 0, stream>>>(A1, inv1);
    bgemm_m<false, true><<<bgrid, bblk, 0, stream>>>(A1, T2h, T2l, T3h, T3l, inv1);    // emb1' = T3
    gw(stream, 1, T1h, T1l, 2048, W1a, 2048, nullptr, T2h, T2l, b1a, 1);   // a-path g2
    gw(stream, 1, T1h, T1l, 2048, W1u, 2048, nullptr, T4h, T4l, b1u, 1);   // u-path g2
    colnorm_k<<<32, 256, 0, stream>>>(A2, inv2);
    bgemm_m<false, true><<<bgrid, bblk, 0, stream>>>(A2, T2h, T2l, T4h, T4l, inv2);    // emb2' = T4

    // ===== Phase 6: affinity 1 =====
    gw(stream, 0, T3h, T3l, 2048, Aaff1, 2048, T1f, nullptr, nullptr, nullptr, 0);
    gemm_bt_f64<<<dim3(4, 4, 32), 256, 0, stream>>>(T1f, T4h, T4l, S);

    sk_fused<<<32, 1024, 0, stream>>>(S, n1);
}

// Round 9
// 4131.144 us; speedup vs baseline: 1.2488x; 1.0350x over previous
//
#include <hip/hip_runtime.h>
#include <math.h>

#define NEGV -1e9f
#define SK_TAU 0.05f

typedef __attribute__((ext_vector_type(4))) float f32x4;
typedef __attribute__((ext_vector_type(8))) short short8;

#define GLDS(g, l) __builtin_amdgcn_global_load_lds( \
    (const __attribute__((address_space(1))) void*)(g), \
    (__attribute__((address_space(3))) void*)(l), 16, 0, 0)

// ---------------- bf16 split helpers ----------------
__device__ inline unsigned bf16rtn(float x) {
    unsigned u = __float_as_uint(x);
    return (u + 0x7FFFu + ((u >> 16) & 1u)) >> 16;
}
__device__ inline float bf2f(short h) {
    return __uint_as_float(((unsigned)(unsigned short)h) << 16);
}
__device__ inline void split1(float x, short& h, short& l) {
    unsigned hu = bf16rtn(x);
    h = (short)hu;
    float r = x - __uint_as_float(hu << 16);
    l = (short)(__float_as_uint(r) >> 16);
}
__device__ inline void cvt4(const float4 v, short4& h, short4& l) {
    unsigned h0 = bf16rtn(v.x), h1 = bf16rtn(v.y), h2 = bf16rtn(v.z), h3 = bf16rtn(v.w);
    h.x = (short)h0; h.y = (short)h1; h.z = (short)h2; h.w = (short)h3;
    float l0 = v.x - __uint_as_float(h0 << 16);
    float l1 = v.y - __uint_as_float(h1 << 16);
    float l2 = v.z - __uint_as_float(h2 << 16);
    float l3 = v.w - __uint_as_float(h3 << 16);
    l.x = (short)(__float_as_uint(l0) >> 16);
    l.y = (short)(__float_as_uint(l1) >> 16);
    l.z = (short)(__float_as_uint(l2) >> 16);
    l.w = (short)(__float_as_uint(l3) >> 16);
}
__device__ inline short8 pack8(const short4 a, const short4 b) {
    short8 r;
    r[0] = a.x; r[1] = a.y; r[2] = a.z; r[3] = a.w;
    r[4] = b.x; r[5] = b.y; r[6] = b.z; r[7] = b.w;
    return r;
}

// ---------------- inv column L1 norm ----------------
__global__ __launch_bounds__(256) void colnorm_k(const float* __restrict__ A,
                                                 float* __restrict__ inv)
{
    int idx = blockIdx.x * 256 + threadIdx.x;
    int b = idx >> 8, m = idx & 255;
    const float* p = A + (long long)b * 65536 + m;
    float s = 0.f;
    #pragma unroll 8
    for (int n = 0; n < 256; ++n) s += fabsf(p[n * 256]);
    inv[idx] = 1.f / fmaxf(s, 1e-12f);
}

// ---------------- fp32 -> split planes ----------------
__global__ __launch_bounds__(256) void split_mat(const float* __restrict__ X,
                                                 short* __restrict__ H,
                                                 short* __restrict__ L, long long n4)
{
    long long i = (long long)blockIdx.x * 256 + threadIdx.x;
    long long stride = (long long)gridDim.x * 256;
    for (; i < n4; i += stride) {
        float4 v = ((const float4*)X)[i];
        short4 h, l;
        cvt4(v, h, l);
        ((short4*)H)[i] = h;
        ((short4*)L)[i] = l;
    }
}

// =====================================================================
// 8-wave 256x256-tile 4-phase split-bf16 GEMM engine:
//   C = epi( [A1 | A2] @ Bf + bias ),  OM 0 = fp32 store, 1 = split store.
// 512 threads (8 waves, wave tile 128x64), BK=32, 128 KB dynamic LDS
// double buffer. Per panel: 4 phases {ds_read frags; staging issue;
// s_barrier; lgkmcnt(0)+sched_barrier; setprio(1); 24 MFMA; setprio(0);
// s_barrier}; vmcnt drained once per panel.
// XCD-aware bijective blockIdx swizzle (T1): default round-robin puts
// the 8 n-blocks sharing an A-panel on 8 different per-XCD L2s ->
// FETCH 573 MB vs 160 ideal, staging loads at HBM latency. Swizzle
// gives XCD x a contiguous 4-m-row stripe; per-panel working set
// (A 128 KB + B 256 KB) fits 4 MB L2. Both A-plane DMAs issued in ph0.
// =====================================================================
template <int OM>
__global__ __launch_bounds__(512, 2) void gemm_w8(
    const short* __restrict__ A1h, const short* __restrict__ A1l,
    const short* __restrict__ A2h, const short* __restrict__ A2l,
    int K1, int lda,
    const float* __restrict__ Bf, int K,
    float* __restrict__ Cf, short* __restrict__ Ch, short* __restrict__ Cl,
    const float* __restrict__ bias, int relu)
{
    extern __shared__ short lds_s[];    // 2 x 32768 shorts = 128 KB

    const int tid = threadIdx.x;
    const int wave = tid >> 6, L = tid & 63;

    // ---- T1: XCD-aware bijective swizzle (nwg divisible by 8) ----
    const int flat = blockIdx.y * gridDim.x + blockIdx.x;
    const int q = (gridDim.x * gridDim.y) >> 3;
    const int swz = (flat & 7) * q + (flat >> 3);
    const int bx = swz % gridDim.x, by = swz / gridDim.x;
    const int m0 = by * 256, n0 = bx * 256;

    const int wm = (wave & 1) * 128, wn = (wave >> 1) * 64;
    const int lm = L & 15, lh = (L >> 4) * 8;
    const int c0 = wave * 2;            // A chunks owned for staging

    long long grow[2];
    #pragma unroll
    for (int c = 0; c < 2; ++c)
        grow[c] = (long long)(m0 + (c0 + c) * 16 + lm) * lda + lh;

    // B staging: thread owns (col, k-half16)
    const int bcol = tid & 255, bkh = tid >> 8;
    const float* bp = Bf + (long long)(bkh * 16) * 2048 + n0 + bcol;
    const int bws = (bcol >> 4) * 512 + (bcol & 15) * 8 + bkh * 256;

    f32x4 acc[8][4];
    #pragma unroll
    for (int i = 0; i < 8; ++i)
        #pragma unroll
        for (int j = 0; j < 4; ++j)
            acc[i][j] = (f32x4){0.f, 0.f, 0.f, 0.f};

    float brA[16];
    short8 AF[4], ALF[4], BFr[4], BLF[4];
    const int abase = (wm >> 4) * 512 + L * 8;
    const int bbase = (wn >> 4) * 512 + L * 8;

    auto GLDS_A = [&](short* buf, int k0, int plane) {
        const short* s; int ko;
        if (k0 < K1) { s = plane ? A1l : A1h; ko = k0; }
        else         { s = plane ? A2l : A2h; ko = k0 - K1; }
        #pragma unroll
        for (int c = 0; c < 2; ++c)
            GLDS(s + grow[c] + ko, buf + plane * 8192 + (c0 + c) * 512);
    };
    auto LOADB = [&](int k0) {
        #pragma unroll
        for (int j = 0; j < 16; ++j)
            brA[j] = bp[((long long)k0 + j) * 2048];
    };
    auto WRITEB = [&](short* buf) {
        #pragma unroll
        for (int ks = 0; ks < 2; ++ks) {
            float4 v0 = {brA[ks * 8 + 0], brA[ks * 8 + 1], brA[ks * 8 + 2], brA[ks * 8 + 3]};
            float4 v1 = {brA[ks * 8 + 4], brA[ks * 8 + 5], brA[ks * 8 + 6], brA[ks * 8 + 7]};
            short4 h0, l0, h1, l1;
            cvt4(v0, h0, l0);
            cvt4(v1, h1, l1);
            *(short8*)(buf + 16384 + bws + ks * 128) = pack8(h0, h1);
            *(short8*)(buf + 24576 + bws + ks * 128) = pack8(l0, l1);
        }
    };

#define RD_A8(H) do { _Pragma("unroll") for (int i_ = 0; i_ < 4; ++i_) { \
        AF[i_]  = *(const short8*)(cur + abase + ((H) * 4 + i_) * 512); \
        ALF[i_] = *(const short8*)(cur + 8192 + abase + ((H) * 4 + i_) * 512); } } while (0)

#define RD_B8(NH) do { _Pragma("unroll") for (int j_ = 0; j_ < 2; ++j_) { \
        BFr[(NH) * 2 + j_] = *(const short8*)(cur + 16384 + bbase + ((NH) * 2 + j_) * 512); \
        BLF[(NH) * 2 + j_] = *(const short8*)(cur + 24576 + bbase + ((NH) * 2 + j_) * 512); } } while (0)

#define MQ8(MH, NH) do { _Pragma("unroll") for (int i_ = 0; i_ < 4; ++i_) \
        _Pragma("unroll") for (int j_ = 0; j_ < 2; ++j_) { \
            acc[(MH)*4+i_][(NH)*2+j_] = __builtin_amdgcn_mfma_f32_16x16x32_bf16(AF[i_],  BFr[(NH)*2+j_], acc[(MH)*4+i_][(NH)*2+j_], 0, 0, 0); \
            acc[(MH)*4+i_][(NH)*2+j_] = __builtin_amdgcn_mfma_f32_16x16x32_bf16(AF[i_],  BLF[(NH)*2+j_], acc[(MH)*4+i_][(NH)*2+j_], 0, 0, 0); \
            acc[(MH)*4+i_][(NH)*2+j_] = __builtin_amdgcn_mfma_f32_16x16x32_bf16(ALF[i_], BFr[(NH)*2+j_], acc[(MH)*4+i_][(NH)*2+j_], 0, 0, 0); } } while (0)

#define PH_IN() do { __builtin_amdgcn_s_barrier(); \
        asm volatile("s_waitcnt lgkmcnt(0)" ::: "memory"); \
        __builtin_amdgcn_sched_barrier(0); \
        __builtin_amdgcn_s_setprio(1); } while (0)
#define PH_OUT() do { __builtin_amdgcn_s_setprio(0); \
        __builtin_amdgcn_s_barrier(); } while (0)

    const int NT = K >> 5;

    // ---- prologue: panel 0 -> buf0, full drain once ----
    LOADB(0);
    GLDS_A(lds_s, 0, 0);
    GLDS_A(lds_s, 0, 1);
    WRITEB(lds_s);
    __syncthreads();

    for (int t = 0; t < NT; ++t) {
        short* cur = lds_s + (t & 1) * 32768;
        short* nxt = lds_s + ((t + 1) & 1) * 32768;
        const bool more = (t + 1) < NT;
        const int kn = (t + 1) << 5;

        // ph0: A-half0 + B-half0 frags; issue ALL next-panel A DMA + B loads
        RD_A8(0); RD_B8(0);
        if (more) { LOADB(kn); GLDS_A(nxt, kn, 0); GLDS_A(nxt, kn, 1); }
        PH_IN(); MQ8(0, 0); PH_OUT();

        // ph1: B-half1 frags
        RD_B8(1);
        PH_IN(); MQ8(0, 1); PH_OUT();

        // ph2: A-half1 frags; convert+write next-panel B to LDS
        RD_A8(1);
        if (more) WRITEB(nxt);
        PH_IN(); MQ8(1, 0); PH_OUT();

        // ph3: pure MFMA; panel boundary drains vmcnt once
        __builtin_amdgcn_s_setprio(1);
        MQ8(1, 1);
        __builtin_amdgcn_s_setprio(0);
        asm volatile("s_waitcnt vmcnt(0)" ::: "memory");
        __builtin_amdgcn_s_barrier();
    }

#undef RD_A8
#undef RD_B8
#undef MQ8
#undef PH_IN
#undef PH_OUT

    // ---- epilogue: C/D layout col = lane&15, row = (lane>>4)*4 + reg ----
    const int lcol = L & 15, lrow = (L >> 4) * 4;
    float bv[4];
    #pragma unroll
    for (int tj = 0; tj < 4; ++tj)
        bv[tj] = bias ? bias[n0 + wn + tj * 16 + lcol] : 0.f;

    #pragma unroll
    for (int ti = 0; ti < 8; ++ti) {
        #pragma unroll
        for (int r = 0; r < 4; ++r) {
            int gr = m0 + wm + ti * 16 + lrow + r;
            #pragma unroll
            for (int tj = 0; tj < 4; ++tj) {
                int gcol = n0 + wn + tj * 16 + lcol;
                float v = acc[ti][tj][r] + bv[tj];
                if (relu) v = fmaxf(v, 0.f);
                long long idx = (long long)gr * 2048 + gcol;
                if (OM == 0) {
                    Cf[idx] = v;
                } else {
                    short hh, ll;
                    split1(v, hh, ll);
                    Ch[idx] = hh;
                    Cl[idx] = ll;
                }
            }
        }
    }
}

// =====================================================================
// Batched MFMA GEMM (proven round-6 engine, unchanged):
//   per batch z: C[256][2048] = A(256x256 fp32, opt colscale) @ B(split)
// =====================================================================
template <bool TA, bool ACC>
__global__ __launch_bounds__(256, 2) void bgemm_m(
    const float* __restrict__ A,
    const short* __restrict__ Bh_, const short* __restrict__ Bl_,
    short* __restrict__ Ch, short* __restrict__ Cl,
    const float* __restrict__ colscale)
{
    __shared__ alignas(16) short lds[2][16384];

    const int tid = threadIdx.x;
    const int wave = tid >> 6, L = tid & 63;
    const int z = blockIdx.z;
    const int n0 = blockIdx.x * 128, m0 = blockIdx.y * 128;
    const int wm = (wave & 1) * 64, wn = (wave >> 1) * 64;
    const long long sB = 524288;
    const float* Az = A + (long long)z * 65536;
    const float* cs = colscale ? colscale + z * 256 : nullptr;

    const int arow = tid & 127, akh = tid >> 7;
    const int aws = (arow >> 4) * 512 + (arow & 15) * 8 + akh * 256;
    const int bws = aws;

    f32x4 acc[4][4];
    #pragma unroll
    for (int i = 0; i < 4; ++i)
        #pragma unroll
        for (int j = 0; j < 4; ++j)
            acc[i][j] = (f32x4){0.f, 0.f, 0.f, 0.f};

    float ar[16];
    short brh[16], brl[16];

    auto LOADA = [&](int k0) {
        #pragma unroll
        for (int j = 0; j < 16; ++j) {
            int kk = k0 + akh * 16 + j;
            float v;
            if (TA) v = Az[(long long)kk * 256 + m0 + arow];
            else    v = Az[(long long)(m0 + arow) * 256 + kk];
            if (!TA && cs) v *= cs[kk];
            ar[j] = v;
        }
    };
    auto LOADBB = [&](int k0) {
        #pragma unroll
        for (int j = 0; j < 16; ++j) {
            long long off = (long long)z * sB +
                            (long long)(k0 + akh * 16 + j) * 2048 + n0 + arow;
            brh[j] = Bh_[off];
            brl[j] = Bl_[off];
        }
    };
    auto WRITES = [&](short* buf) {
        #pragma unroll
        for (int ks = 0; ks < 2; ++ks) {
            float4 v0 = {ar[ks * 8 + 0], ar[ks * 8 + 1], ar[ks * 8 + 2], ar[ks * 8 + 3]};
            float4 v1 = {ar[ks * 8 + 4], ar[ks * 8 + 5], ar[ks * 8 + 6], ar[ks * 8 + 7]};
            short4 h0, l0, h1, l1;
            cvt4(v0, h0, l0);
            cvt4(v1, h1, l1);
            *(short8*)(buf + aws + ks * 128)        = pack8(h0, h1);
            *(short8*)(buf + 4096 + aws + ks * 128) = pack8(l0, l1);
        }
        #pragma unroll
        for (int ks = 0; ks < 2; ++ks) {
            short8 h, l;
            #pragma unroll
            for (int i = 0; i < 8; ++i) { h[i] = brh[ks * 8 + i]; l[i] = brl[ks * 8 + i]; }
            *(short8*)(buf + 8192  + bws + ks * 128) = h;
            *(short8*)(buf + 12288 + bws + ks * 128) = l;
        }
    };

    const int ab = (wm >> 4) * 512 + L * 8;
    const int bb = (wn >> 4) * 512 + L * 8;
    auto COMPUTE = [&](const short* buf) {
        const short* AhS = buf;
        const short* AlS = buf + 4096;
        const short* BhS = buf + 8192;
        const short* BlS = buf + 12288;
        short8 AF[4], ALF[4], BFr[4], BLF[4];
        #pragma unroll
        for (int t = 0; t < 4; ++t) {
            AF[t]  = *(const short8*)(AhS + ab + t * 512);
            ALF[t] = *(const short8*)(AlS + ab + t * 512);
            BFr[t] = *(const short8*)(BhS + bb + t * 512);
            BLF[t] = *(const short8*)(BlS + bb + t * 512);
        }
        #pragma unroll
        for (int ti = 0; ti < 4; ++ti)
            #pragma unroll
            for (int tj = 0; tj < 4; ++tj) {
                acc[ti][tj] = __builtin_amdgcn_mfma_f32_16x16x32_bf16(AF[ti],  BFr[tj], acc[ti][tj], 0, 0, 0);
                acc[ti][tj] = __builtin_amdgcn_mfma_f32_16x16x32_bf16(AF[ti],  BLF[tj], acc[ti][tj], 0, 0, 0);
                acc[ti][tj] = __builtin_amdgcn_mfma_f32_16x16x32_bf16(ALF[ti], BFr[tj], acc[ti][tj], 0, 0, 0);
            }
    };

    LOADA(0);
    LOADBB(0);
    #pragma unroll
    for (int t = 0; t < 8; ++t) {
        WRITES(lds[t & 1]);
        __syncthreads();
        if (t < 7) { LOADA((t + 1) * 32); LOADBB((t + 1) * 32); }
        COMPUTE(lds[t & 1]);
    }

    const int lcol = L & 15, lrow = (L >> 4) * 4;
    #pragma unroll
    for (int ti = 0; ti < 4; ++ti) {
        #pragma unroll
        for (int r = 0; r < 4; ++r) {
            int gr = m0 + wm + ti * 16 + lrow + r;
            long long base = (long long)z * sB + (long long)gr * 2048;
            #pragma unroll
            for (int tj = 0; tj < 4; ++tj) {
                int gcol = n0 + wn + tj * 16 + lcol;
                long long idx = base + gcol;
                float v = acc[ti][tj][r];
                if (ACC) v += bf2f(Ch[idx]) + bf2f(Cl[idx]);
                short hh, ll;
                split1(v, hh, ll);
                Ch[idx] = hh;
                Cl[idx] = ll;
            }
        }
    }
}

// ---------------- fp64-accumulate affinity GEMM ----------------
__global__ __launch_bounds__(256) void gemm_bt_f64(
    const float* __restrict__ A,
    const short* __restrict__ Bh_, const short* __restrict__ Bl_,
    float* __restrict__ C)
{
    __shared__ float As[16][65];
    __shared__ float Bs[16][65];

    const int K = 2048;
    int z = blockIdx.z;
    const float* Az = A + (long long)z * 524288;
    C += (long long)z * 65536;

    int n0 = blockIdx.x * 64;
    int m0 = blockIdx.y * 64;
    int tid = threadIdx.x;
    int tx = tid & 15;
    int ty = tid >> 4;

    double acc[4][4];
    #pragma unroll
    for (int i = 0; i < 4; ++i)
        #pragma unroll
        for (int j = 0; j < 4; ++j) acc[i][j] = 0.0;

    int r  = tid >> 2;
    int c4 = (tid & 3) * 4;

    for (int k0 = 0; k0 < K; k0 += 16) {
        {
            const float4 v = *(const float4*)(Az + (long long)(m0 + r) * K + k0 + c4);
            As[c4 + 0][r] = v.x; As[c4 + 1][r] = v.y;
            As[c4 + 2][r] = v.z; As[c4 + 3][r] = v.w;
        }
        {
            long long off = (long long)z * 524288 + (long long)(n0 + r) * K + k0 + c4;
            short4 h = *(const short4*)(Bh_ + off);
            short4 l = *(const short4*)(Bl_ + off);
            Bs[c4 + 0][r] = bf2f(h.x) + bf2f(l.x);
            Bs[c4 + 1][r] = bf2f(h.y) + bf2f(l.y);
            Bs[c4 + 2][r] = bf2f(h.z) + bf2f(l.z);
            Bs[c4 + 3][r] = bf2f(h.w) + bf2f(l.w);
        }
        __syncthreads();

        #pragma unroll
        for (int kk = 0; kk < 16; ++kk) {
            double a[4], b[4];
            #pragma unroll
            for (int i = 0; i < 4; ++i) a[i] = (double)As[kk][ty + 16 * i];
            #pragma unroll
            for (int j = 0; j < 4; ++j) b[j] = (double)Bs[kk][tx + 16 * j];
            #pragma unroll
            for (int i = 0; i < 4; ++i)
                #pragma unroll
                for (int j = 0; j < 4; ++j)
                    acc[i][j] = fma(a[i], b[j], acc[i][j]);
        }
        __syncthreads();
    }

    #pragma unroll
    for (int i = 0; i < 4; ++i) {
        int rowl = m0 + ty + 16 * i;
        #pragma unroll
        for (int j = 0; j < 4; ++j)
            C[(long long)rowl * 256 + n0 + tx + 16 * j] = (float)acc[i][j];
    }
}

// =====================================================================
// Fused Sinkhorn: one 1024-thread block per batch; S register-resident.
// =====================================================================
__global__ __launch_bounds__(1024, 4) void sk_fused(float* __restrict__ S,
                                                    const int* __restrict__ n1)
{
    __shared__ float pmax[16][256];
    __shared__ float psum[16][256];
    __shared__ float lseS[256];

    const int b = blockIdx.x;
    const int tid = threadIdx.x;
    const int w = tid >> 6, l = tid & 63;
    const int lim = n1[b];
    float* Sb = S + (long long)b * 65536;

    float4 v[16];
    #pragma unroll
    for (int r = 0; r < 16; ++r) {
        int n = w * 16 + r;
        if (n < lim) {
            float4 x = *(const float4*)(Sb + n * 256 + l * 4);
            v[r].x = x.x / SK_TAU; v[r].y = x.y / SK_TAU;
            v[r].z = x.z / SK_TAU; v[r].w = x.w / SK_TAU;
        } else {
            v[r] = (float4){NEGV, NEGV, NEGV, NEGV};
        }
    }

    for (int it = 0; it < 10; ++it) {
        if ((it & 1) == 0) {
            #pragma unroll
            for (int r = 0; r < 16; ++r) {
                if (w * 16 + r >= lim) continue;
                float m = fmaxf(fmaxf(v[r].x, v[r].y), fmaxf(v[r].z, v[r].w));
                #pragma unroll
                for (int off = 1; off < 64; off <<= 1) m = fmaxf(m, __shfl_xor(m, off));
                float s = expf(v[r].x - m) + expf(v[r].y - m) +
                          expf(v[r].z - m) + expf(v[r].w - m);
                #pragma unroll
                for (int off = 1; off < 64; off <<= 1) s += __shfl_xor(s, off);
                float lse = m + logf(s);
                v[r].x -= lse; v[r].y -= lse; v[r].z -= lse; v[r].w -= lse;
            }
        } else {
            float cm[4] = {-3.4e38f, -3.4e38f, -3.4e38f, -3.4e38f};
            #pragma unroll
            for (int r = 0; r < 16; ++r) {
                cm[0] = fmaxf(cm[0], v[r].x); cm[1] = fmaxf(cm[1], v[r].y);
                cm[2] = fmaxf(cm[2], v[r].z); cm[3] = fmaxf(cm[3], v[r].w);
            }
            float cs[4] = {0.f, 0.f, 0.f, 0.f};
            #pragma unroll
            for (int r = 0; r < 16; ++r) {
                cs[0] += expf(v[r].x - cm[0]); cs[1] += expf(v[r].y - cm[1]);
                cs[2] += expf(v[r].z - cm[2]); cs[3] += expf(v[r].w - cm[3]);
            }
            #pragma unroll
            for (int j = 0; j < 4; ++j) {
                pmax[w][l * 4 + j] = cm[j];
                psum[w][l * 4 + j] = cs[j];
            }
            __syncthreads();
            if (tid < 256) {
                float m = -3.4e38f, s = 0.f;
                #pragma unroll
                for (int ww = 0; ww < 16; ++ww) {
                    float pm = pmax[ww][tid], ps = psum[ww][tid];
                    float nm = fmaxf(m, pm);
                    s = s * expf(m - nm) + ps * expf(pm - nm);
                    m = nm;
                }
                lseS[tid] = m + logf(s);
            }
            __syncthreads();
            float l0 = lseS[l * 4 + 0], l1 = lseS[l * 4 + 1];
            float l2 = lseS[l * 4 + 2], l3 = lseS[l * 4 + 3];
            #pragma unroll
            for (int r = 0; r < 16; ++r) {
                if (w * 16 + r >= lim) continue;
                v[r].x -= l0; v[r].y -= l1; v[r].z -= l2; v[r].w -= l3;
            }
        }
    }

    #pragma unroll
    for (int r = 0; r < 16; ++r) {
        int n = w * 16 + r;
        float4 o;
        if (n < lim) {
            o.x = expf(v[r].x); o.y = expf(v[r].y);
            o.z = expf(v[r].z); o.w = expf(v[r].w);
        } else {
            o = (float4){0.f, 0.f, 0.f, 0.f};
        }
        *(float4*)(Sb + n * 256 + l * 4) = o;
    }
}

// ---------------- launch wrappers ----------------
static void set_lds_attr() {
    static bool done = false;
    if (done) return;
    hipFuncSetAttribute((const void*)gemm_w8<0>,
                        hipFuncAttributeMaxDynamicSharedMemorySize, 131072);
    hipFuncSetAttribute((const void*)gemm_w8<1>,
                        hipFuncAttributeMaxDynamicSharedMemorySize, 131072);
    done = true;
}

static void gw(hipStream_t st, int om, const short* Ah, const short* Al, int lda,
               const float* Bf, int K,
               float* Cf, short* Ch, short* Cl, const float* bias, int relu)
{
    set_lds_attr();
    dim3 grid(8, 32), block(512);
    if (om == 0)
        gemm_w8<0><<<grid, block, 131072, st>>>(Ah, Al, Ah, Al, K, lda, Bf, K,
                                                Cf, nullptr, nullptr, bias, relu);
    else
        gemm_w8<1><<<grid, block, 131072, st>>>(Ah, Al, Ah, Al, K, lda, Bf, K,
                                                nullptr, Ch, Cl, bias, relu);
}

static void gwcat(hipStream_t st, const short* A1h, const short* A1l,
                  const short* A2h, const short* A2l,
                  const float* Bf, short* Ch, short* Cl, const float* bias)
{
    set_lds_attr();
    dim3 grid(8, 32), block(512);
    gemm_w8<1><<<grid, block, 131072, st>>>(A1h, A1l, A2h, A2l, 2048, 2048, Bf, 4096,
                                            nullptr, Ch, Cl, bias, 0);
}

// ---------------- driver ----------------
extern "C" void kernel_launch(void* const* d_in, const int* in_sizes, int n_in,
                              void* d_out, int out_size, void* d_ws, size_t ws_size,
                              hipStream_t stream)
{
    const float* feat1 = (const float*)d_in[0];
    const float* feat2 = (const float*)d_in[1];
    const float* A1    = (const float*)d_in[2];
    const float* A2    = (const float*)d_in[3];
    const int*   n1    = (const int*)d_in[4];
    const float* W0a = (const float*)d_in[8];  const float* b0a = (const float*)d_in[9];
    const float* W0u = (const float*)d_in[10]; const float* b0u = (const float*)d_in[11];
    const float* W1a = (const float*)d_in[12]; const float* b1a = (const float*)d_in[13];
    const float* W1u = (const float*)d_in[14]; const float* b1u = (const float*)d_in[15];
    const float* Wc  = (const float*)d_in[16]; const float* bc  = (const float*)d_in[17];
    const float* Aaff0 = (const float*)d_in[18];
    const float* Aaff1 = (const float*)d_in[19];

    const long long TSZ = 16777216LL;
    const long long PL  = 16777216LL;
    const long long PF  = 8388608LL;

    float* T1f = (float*)d_ws;
    float* T2f = T1f + TSZ;
    float* T3f = T2f + TSZ;
    float* T4f = T3f + TSZ;
    short *T1h = (short*)T1f, *T1l = T1h + PL;
    short *T2h = (short*)T2f, *T2l = T2h + PL;
    short *T3h = (short*)T3f, *T3l = T3h + PL;
    short *T4h = (short*)T4f, *T4l = T4h + PL;

    short* f1h = (short*)T4f;      short* f1l = f1h + PF;
    short* f2h = f1h + 2 * PF;     short* f2l = f1h + 3 * PF;
    float* invA = (float*)T4f;     // overlaps f1h rows: written only after
    float* invB = invA + 8192;     // the last f1 read (ordering below)

    float* S    = (float*)d_out;
    float* inv1 = S;
    float* inv2 = S + 8192;

    dim3 bgrid(16, 2, 32), bblk(256);

    // ===== Phase 0: split feats =====
    split_mat<<<2048, 256, 0, stream>>>(feat1, f1h, f1l, 8192LL * 1024 / 4);
    split_mat<<<2048, 256, 0, stream>>>(feat2, f2h, f2l, 8192LL * 1024 / 4);

    // ===== Phase 1: gconv layer 0 (K=1024, lda=1024) =====
    gw(stream, 1, f1h, f1l, 1024, W0u, 1024, nullptr, T1h, T1l, b0u, 1);
    gw(stream, 1, f2h, f2l, 1024, W0u, 1024, nullptr, T2h, T2l, b0u, 1);
    gw(stream, 1, f1h, f1l, 1024, W0a, 1024, nullptr, T3h, T3l, b0a, 1);   // last f1 read
    colnorm_k<<<32, 256, 0, stream>>>(A1, invA);
    colnorm_k<<<32, 256, 0, stream>>>(A2, invB);
    bgemm_m<false, true><<<bgrid, bblk, 0, stream>>>(A1, T3h, T3l, T1h, T1l, invA);
    gw(stream, 1, f2h, f2l, 1024, W0a, 1024, nullptr, T3h, T3l, b0a, 1);
    bgemm_m<false, true><<<bgrid, bblk, 0, stream>>>(A2, T3h, T3l, T2h, T2l, invB);

    // ===== Phase 2: affinity 0 =====
    gw(stream, 0, T1h, T1l, 2048, Aaff0, 2048, T3f, nullptr, nullptr, nullptr, 0);
    gemm_bt_f64<<<dim3(4, 4, 32), 256, 0, stream>>>(T3f, T2h, T2l, S);

    sk_fused<<<32, 1024, 0, stream>>>(S, n1);

    // ===== Phase 4: cross-graph update =====
    bgemm_m<false, false><<<bgrid, bblk, 0, stream>>>(S, T2h, T2l, T3h, T3l, nullptr); // c1 = S @ emb2
    gwcat(stream, T1h, T1l, T3h, T3l, Wc, T4h, T4l, bc);   // new1 = [emb1|c1]@Wc+bc
    bgemm_m<true, false><<<bgrid, bblk, 0, stream>>>(S, T1h, T1l, T3h, T3l, nullptr);  // c2 = S^T @ emb1
    gwcat(stream, T2h, T2l, T3h, T3l, Wc, T1h, T1l, bc);   // new2 = [emb2|c2]@Wc+bc

    // ===== Phase 5: gconv layer 1 (K=2048, lda=2048) =====
    gw(stream, 1, T4h, T4l, 2048, W1a, 2048, nullptr, T2h, T2l, b1a, 1);   // a-path g1
    gw(stream, 1, T4h, T4l, 2048, W1u, 2048, nullptr, T3h, T3l, b1u, 1);   // u-path g1
    colnorm_k<<<32, 256, 0, stream>>>(A1, inv1);
    bgemm_m<false, true><<<bgrid, bblk, 0, stream>>>(A1, T2h, T2l, T3h, T3l, inv1);    // emb1' = T3
    gw(stream, 1, T1h, T1l, 2048, W1a, 2048, nullptr, T2h, T2l, b1a, 1);   // a-path g2
    gw(stream, 1, T1h, T1l, 2048, W1u, 2048, nullptr, T4h, T4l, b1u, 1);   // u-path g2
    colnorm_k<<<32, 256, 0, stream>>>(A2, inv2);
    bgemm_m<false, true><<<bgrid, bblk, 0, stream>>>(A2, T2h, T2l, T4h, T4l, inv2);    // emb2' = T4

    // ===== Phase 6: affinity 1 =====
    gw(stream, 0, T3h, T3l, 2048, Aaff1, 2048, T1f, nullptr, nullptr, nullptr, 0);
    gemm_bt_f64<<<dim3(4, 4, 32), 256, 0, stream>>>(T1f, T4h, T4l, S);

    sk_fused<<<32, 1024, 0, stream>>>(S, n1);
}

// Round 12
// 3741.014 us; speedup vs baseline: 1.3791x; 1.1043x over previous
//
#include <hip/hip_runtime.h>
#include <math.h>

#define NEGV -1e9f
#define SK_TAU 0.05f

typedef __attribute__((ext_vector_type(4))) float f32x4;
typedef __attribute__((ext_vector_type(8))) short short8;

#define GLDS(g, l) __builtin_amdgcn_global_load_lds( \
    (const __attribute__((address_space(1))) void*)(g), \
    (__attribute__((address_space(3))) void*)(l), 16, 0, 0)

// ---------------- bf16 split helpers ----------------
__device__ inline unsigned bf16rtn(float x) {
    unsigned u = __float_as_uint(x);
    return (u + 0x7FFFu + ((u >> 16) & 1u)) >> 16;
}
__device__ inline float bf2f(short h) {
    return __uint_as_float(((unsigned)(unsigned short)h) << 16);
}
__device__ inline void split1(float x, short& h, short& l) {
    unsigned hu = bf16rtn(x);
    h = (short)hu;
    float r = x - __uint_as_float(hu << 16);
    l = (short)(__float_as_uint(r) >> 16);
}
__device__ inline void cvt4(const float4 v, short4& h, short4& l) {
    unsigned h0 = bf16rtn(v.x), h1 = bf16rtn(v.y), h2 = bf16rtn(v.z), h3 = bf16rtn(v.w);
    h.x = (short)h0; h.y = (short)h1; h.z = (short)h2; h.w = (short)h3;
    float l0 = v.x - __uint_as_float(h0 << 16);
    float l1 = v.y - __uint_as_float(h1 << 16);
    float l2 = v.z - __uint_as_float(h2 << 16);
    float l3 = v.w - __uint_as_float(h3 << 16);
    l.x = (short)(__float_as_uint(l0) >> 16);
    l.y = (short)(__float_as_uint(l1) >> 16);
    l.z = (short)(__float_as_uint(l2) >> 16);
    l.w = (short)(__float_as_uint(l3) >> 16);
}
__device__ inline short8 pack8(const short4 a, const short4 b) {
    short8 r;
    r[0] = a.x; r[1] = a.y; r[2] = a.z; r[3] = a.w;
    r[4] = b.x; r[5] = b.y; r[6] = b.z; r[7] = b.w;
    return r;
}

// ---------------- inv column L1 norm ----------------
__global__ __launch_bounds__(256) void colnorm_k(const float* __restrict__ A,
                                                 float* __restrict__ inv)
{
    int idx = blockIdx.x * 256 + threadIdx.x;
    int b = idx >> 8, m = idx & 255;
    const float* p = A + (long long)b * 65536 + m;
    float s = 0.f;
    #pragma unroll 8
    for (int n = 0; n < 256; ++n) s += fabsf(p[n * 256]);
    inv[idx] = 1.f / fmaxf(s, 1e-12f);
}

// ---------------- fp32 -> split planes ----------------
__global__ __launch_bounds__(256) void split_mat(const float* __restrict__ X,
                                                 short* __restrict__ H,
                                                 short* __restrict__ L, long long n4)
{
    long long i = (long long)blockIdx.x * 256 + threadIdx.x;
    long long stride = (long long)gridDim.x * 256;
    for (; i < n4; i += stride) {
        float4 v = ((const float4*)X)[i];
        short4 h, l;
        cvt4(v, h, l);
        ((short4*)H)[i] = h;
        ((short4*)L)[i] = l;
    }
}

// =====================================================================
// 8-wave 256x256-tile split-bf16 GEMM engine, free-scheduled panel:
//   C = epi( [A1 | A2] @ Bf + bias ),  OM 0 = fp32 store, 1 = split store.
// 512 threads (8 waves, wave tile 128x64), BK=32, 128 KB dynamic LDS
// double buffer, T1 XCD-aware bijective swizzle (r9: FETCH 573->197 MB).
// De-lockstepped: no intra-panel barriers/pins; one vmcnt(0)+lgkmcnt(0)
// +barrier per panel boundary. cur read-only, nxt write-only within a
// panel -> no intra-panel hazard. MFMA order unchanged -> identical
// numerics.
// =====================================================================
template <int OM>
__global__ __launch_bounds__(512, 2) void gemm_w8(
    const short* __restrict__ A1h, const short* __restrict__ A1l,
    const short* __restrict__ A2h, const short* __restrict__ A2l,
    int K1, int lda,
    const float* __restrict__ Bf, int K,
    float* __restrict__ Cf, short* __restrict__ Ch, short* __restrict__ Cl,
    const float* __restrict__ bias, int relu)
{
    extern __shared__ short lds_s[];    // 2 x 32768 shorts = 128 KB

    const int tid = threadIdx.x;
    const int wave = tid >> 6, L = tid & 63;

    // ---- T1: XCD-aware bijective swizzle (nwg divisible by 8) ----
    const int flat = blockIdx.y * gridDim.x + blockIdx.x;
    const int q = (gridDim.x * gridDim.y) >> 3;
    const int swz = (flat & 7) * q + (flat >> 3);
    const int bx = swz % gridDim.x, by = swz / gridDim.x;
    const int m0 = by * 256, n0 = bx * 256;

    const int wm = (wave & 1) * 128, wn = (wave >> 1) * 64;
    const int lm = L & 15, lh = (L >> 4) * 8;
    const int c0 = wave * 2;            // A chunks owned for staging

    long long grow[2];
    #pragma unroll
    for (int c = 0; c < 2; ++c)
        grow[c] = (long long)(m0 + (c0 + c) * 16 + lm) * lda + lh;

    // B staging: thread owns (col, k-half16)
    const int bcol = tid & 255, bkh = tid >> 8;
    const float* bp = Bf + (long long)(bkh * 16) * 2048 + n0 + bcol;
    const int bws = (bcol >> 4) * 512 + (bcol & 15) * 8 + bkh * 256;

    f32x4 acc[8][4];
    #pragma unroll
    for (int i = 0; i < 8; ++i)
        #pragma unroll
        for (int j = 0; j < 4; ++j)
            acc[i][j] = (f32x4){0.f, 0.f, 0.f, 0.f};

    float brA[16];
    short8 AF[4], ALF[4], BFr[4], BLF[4];
    const int abase = (wm >> 4) * 512 + L * 8;
    const int bbase = (wn >> 4) * 512 + L * 8;

    auto GLDS_A = [&](short* buf, int k0, int plane) {
        const short* s; int ko;
        if (k0 < K1) { s = plane ? A1l : A1h; ko = k0; }
        else         { s = plane ? A2l : A2h; ko = k0 - K1; }
        #pragma unroll
        for (int c = 0; c < 2; ++c)
            GLDS(s + grow[c] + ko, buf + plane * 8192 + (c0 + c) * 512);
    };
    auto LOADB = [&](int k0) {
        #pragma unroll
        for (int j = 0; j < 16; ++j)
            brA[j] = bp[((long long)k0 + j) * 2048];
    };
    auto WRITEB = [&](short* buf) {
        #pragma unroll
        for (int ks = 0; ks < 2; ++ks) {
            float4 v0 = {brA[ks * 8 + 0], brA[ks * 8 + 1], brA[ks * 8 + 2], brA[ks * 8 + 3]};
            float4 v1 = {brA[ks * 8 + 4], brA[ks * 8 + 5], brA[ks * 8 + 6], brA[ks * 8 + 7]};
            short4 h0, l0, h1, l1;
            cvt4(v0, h0, l0);
            cvt4(v1, h1, l1);
            *(short8*)(buf + 16384 + bws + ks * 128) = pack8(h0, h1);
            *(short8*)(buf + 24576 + bws + ks * 128) = pack8(l0, l1);
        }
    };

#define RD_A8(H) do { _Pragma("unroll") for (int i_ = 0; i_ < 4; ++i_) { \
        AF[i_]  = *(const short8*)(cur + abase + ((H) * 4 + i_) * 512); \
        ALF[i_] = *(const short8*)(cur + 8192 + abase + ((H) * 4 + i_) * 512); } } while (0)

#define RD_B8(NH) do { _Pragma("unroll") for (int j_ = 0; j_ < 2; ++j_) { \
        BFr[(NH) * 2 + j_] = *(const short8*)(cur + 16384 + bbase + ((NH) * 2 + j_) * 512); \
        BLF[(NH) * 2 + j_] = *(const short8*)(cur + 24576 + bbase + ((NH) * 2 + j_) * 512); } } while (0)

#define MQ8(MH, NH) do { _Pragma("unroll") for (int i_ = 0; i_ < 4; ++i_) \
        _Pragma("unroll") for (int j_ = 0; j_ < 2; ++j_) { \
            acc[(MH)*4+i_][(NH)*2+j_] = __builtin_amdgcn_mfma_f32_16x16x32_bf16(AF[i_],  BFr[(NH)*2+j_], acc[(MH)*4+i_][(NH)*2+j_], 0, 0, 0); \
            acc[(MH)*4+i_][(NH)*2+j_] = __builtin_amdgcn_mfma_f32_16x16x32_bf16(AF[i_],  BLF[(NH)*2+j_], acc[(MH)*4+i_][(NH)*2+j_], 0, 0, 0); \
            acc[(MH)*4+i_][(NH)*2+j_] = __builtin_amdgcn_mfma_f32_16x16x32_bf16(ALF[i_], BFr[(NH)*2+j_], acc[(MH)*4+i_][(NH)*2+j_], 0, 0, 0); } } while (0)

    const int NT = K >> 5;

    // ---- prologue: panel 0 -> buf0, full drain once ----
    LOADB(0);
    GLDS_A(lds_s, 0, 0);
    GLDS_A(lds_s, 0, 1);
    WRITEB(lds_s);
    __syncthreads();

    for (int t = 0; t < NT; ++t) {
        short* cur = lds_s + (t & 1) * 32768;
        short* nxt = lds_s + ((t + 1) & 1) * 32768;
        const bool more = (t + 1) < NT;
        const int kn = (t + 1) << 5;

        // issue all next-panel staging up front: max vmem slack
        if (more) { LOADB(kn); GLDS_A(nxt, kn, 0); GLDS_A(nxt, kn, 1); }

        // compute: compiler interleaves ds_reads / cvt VALU with MFMA
        RD_A8(0); RD_B8(0);
        MQ8(0, 0);
        RD_B8(1);
        MQ8(0, 1);
        RD_A8(1);
        MQ8(1, 0);
        if (more) WRITEB(nxt);
        MQ8(1, 1);

        // panel boundary: nxt fully staged (vmcnt: DMA; lgkm: ds_writes)
        // and cur frag reads retired before buffer swap
        asm volatile("s_waitcnt vmcnt(0) lgkmcnt(0)" ::: "memory");
        __builtin_amdgcn_s_barrier();
    }

#undef RD_A8
#undef RD_B8
#undef MQ8

    // ---- epilogue: C/D layout col = lane&15, row = (lane>>4)*4 + reg ----
    const int lcol = L & 15, lrow = (L >> 4) * 4;
    float bv[4];
    #pragma unroll
    for (int tj = 0; tj < 4; ++tj)
        bv[tj] = bias ? bias[n0 + wn + tj * 16 + lcol] : 0.f;

    #pragma unroll
    for (int ti = 0; ti < 8; ++ti) {
        #pragma unroll
        for (int r = 0; r < 4; ++r) {
            int gr = m0 + wm + ti * 16 + lrow + r;
            #pragma unroll
            for (int tj = 0; tj < 4; ++tj) {
                int gcol = n0 + wn + tj * 16 + lcol;
                float v = acc[ti][tj][r] + bv[tj];
                if (relu) v = fmaxf(v, 0.f);
                long long idx = (long long)gr * 2048 + gcol;
                if (OM == 0) {
                    Cf[idx] = v;
                } else {
                    short hh, ll;
                    split1(v, hh, ll);
                    Ch[idx] = hh;
                    Cl[idx] = ll;
                }
            }
        }
    }
}

// =====================================================================
// Batched MFMA GEMM (proven round-6 engine, unchanged):
//   per batch z: C[256][2048] = A(256x256 fp32, opt colscale) @ B(split)
// =====================================================================
template <bool TA, bool ACC>
__global__ __launch_bounds__(256, 2) void bgemm_m(
    const float* __restrict__ A,
    const short* __restrict__ Bh_, const short* __restrict__ Bl_,
    short* __restrict__ Ch, short* __restrict__ Cl,
    const float* __restrict__ colscale)
{
    __shared__ alignas(16) short lds[2][16384];

    const int tid = threadIdx.x;
    const int wave = tid >> 6, L = tid & 63;
    const int z = blockIdx.z;
    const int n0 = blockIdx.x * 128, m0 = blockIdx.y * 128;
    const int wm = (wave & 1) * 64, wn = (wave >> 1) * 64;
    const long long sB = 524288;
    const float* Az = A + (long long)z * 65536;
    const float* cs = colscale ? colscale + z * 256 : nullptr;

    const int arow = tid & 127, akh = tid >> 7;
    const int aws = (arow >> 4) * 512 + (arow & 15) * 8 + akh * 256;
    const int bws = aws;

    f32x4 acc[4][4];
    #pragma unroll
    for (int i = 0; i < 4; ++i)
        #pragma unroll
        for (int j = 0; j < 4; ++j)
            acc[i][j] = (f32x4){0.f, 0.f, 0.f, 0.f};

    float ar[16];
    short brh[16], brl[16];

    auto LOADA = [&](int k0) {
        #pragma unroll
        for (int j = 0; j < 16; ++j) {
            int kk = k0 + akh * 16 + j;
            float v;
            if (TA) v = Az[(long long)kk * 256 + m0 + arow];
            else    v = Az[(long long)(m0 + arow) * 256 + kk];
            if (!TA && cs) v *= cs[kk];
            ar[j] = v;
        }
    };
    auto LOADBB = [&](int k0) {
        #pragma unroll
        for (int j = 0; j < 16; ++j) {
            long long off = (long long)z * sB +
                            (long long)(k0 + akh * 16 + j) * 2048 + n0 + arow;
            brh[j] = Bh_[off];
            brl[j] = Bl_[off];
        }
    };
    auto WRITES = [&](short* buf) {
        #pragma unroll
        for (int ks = 0; ks < 2; ++ks) {
            float4 v0 = {ar[ks * 8 + 0], ar[ks * 8 + 1], ar[ks * 8 + 2], ar[ks * 8 + 3]};
            float4 v1 = {ar[ks * 8 + 4], ar[ks * 8 + 5], ar[ks * 8 + 6], ar[ks * 8 + 7]};
            short4 h0, l0, h1, l1;
            cvt4(v0, h0, l0);
            cvt4(v1, h1, l1);
            *(short8*)(buf + aws + ks * 128)        = pack8(h0, h1);
            *(short8*)(buf + 4096 + aws + ks * 128) = pack8(l0, l1);
        }
        #pragma unroll
        for (int ks = 0; ks < 2; ++ks) {
            short8 h, l;
            #pragma unroll
            for (int i = 0; i < 8; ++i) { h[i] = brh[ks * 8 + i]; l[i] = brl[ks * 8 + i]; }
            *(short8*)(buf + 8192  + bws + ks * 128) = h;
            *(short8*)(buf + 12288 + bws + ks * 128) = l;
        }
    };

    const int ab = (wm >> 4) * 512 + L * 8;
    const int bb = (wn >> 4) * 512 + L * 8;
    auto COMPUTE = [&](const short* buf) {
        const short* AhS = buf;
        const short* AlS = buf + 4096;
        const short* BhS = buf + 8192;
        const short* BlS = buf + 12288;
        short8 AF[4], ALF[4], BFr[4], BLF[4];
        #pragma unroll
        for (int t = 0; t < 4; ++t) {
            AF[t]  = *(const short8*)(AhS + ab + t * 512);
            ALF[t] = *(const short8*)(AlS + ab + t * 512);
            BFr[t] = *(const short8*)(BhS + bb + t * 512);
            BLF[t] = *(const short8*)(BlS + bb + t * 512);
        }
        #pragma unroll
        for (int ti = 0; ti < 4; ++ti)
            #pragma unroll
            for (int tj = 0; tj < 4; ++tj) {
                acc[ti][tj] = __builtin_amdgcn_mfma_f32_16x16x32_bf16(AF[ti],  BFr[tj], acc[ti][tj], 0, 0, 0);
                acc[ti][tj] = __builtin_amdgcn_mfma_f32_16x16x32_bf16(AF[ti],  BLF[tj], acc[ti][tj], 0, 0, 0);
                acc[ti][tj] = __builtin_amdgcn_mfma_f32_16x16x32_bf16(ALF[ti], BFr[tj], acc[ti][tj], 0, 0, 0);
            }
    };

    LOADA(0);
    LOADBB(0);
    #pragma unroll
    for (int t = 0; t < 8; ++t) {
        WRITES(lds[t & 1]);
        __syncthreads();
        if (t < 7) { LOADA((t + 1) * 32); LOADBB((t + 1) * 32); }
        COMPUTE(lds[t & 1]);
    }

    const int lcol = L & 15, lrow = (L >> 4) * 4;
    #pragma unroll
    for (int ti = 0; ti < 4; ++ti) {
        #pragma unroll
        for (int r = 0; r < 4; ++r) {
            int gr = m0 + wm + ti * 16 + lrow + r;
            long long base = (long long)z * sB + (long long)gr * 2048;
            #pragma unroll
            for (int tj = 0; tj < 4; ++tj) {
                int gcol = n0 + wn + tj * 16 + lcol;
                long long idx = base + gcol;
                float v = acc[ti][tj][r];
                if (ACC) v += bf2f(Ch[idx]) + bf2f(Cl[idx]);
                short hh, ll;
                split1(v, hh, ll);
                Ch[idx] = hh;
                Cl[idx] = ll;
            }
        }
    }
}

// ---------------- fp64-accumulate affinity GEMM ----------------
__global__ __launch_bounds__(256) void gemm_bt_f64(
    const float* __restrict__ A,
    const short* __restrict__ Bh_, const short* __restrict__ Bl_,
    float* __restrict__ C)
{
    __shared__ float As[16][65];
    __shared__ float Bs[16][65];

    const int K = 2048;
    int z = blockIdx.z;
    const float* Az = A + (long long)z * 524288;
    C += (long long)z * 65536;

    int n0 = blockIdx.x * 64;
    int m0 = blockIdx.y * 64;
    int tid = threadIdx.x;
    int tx = tid & 15;
    int ty = tid >> 4;

    double acc[4][4];
    #pragma unroll
    for (int i = 0; i < 4; ++i)
        #pragma unroll
        for (int j = 0; j < 4; ++j) acc[i][j] = 0.0;

    int r  = tid >> 2;
    int c4 = (tid & 3) * 4;

    for (int k0 = 0; k0 < K; k0 += 16) {
        {
            const float4 v = *(const float4*)(Az + (long long)(m0 + r) * K + k0 + c4);
            As[c4 + 0][r] = v.x; As[c4 + 1][r] = v.y;
            As[c4 + 2][r] = v.z; As[c4 + 3][r] = v.w;
        }
        {
            long long off = (long long)z * 524288 + (long long)(n0 + r) * K + k0 + c4;
            short4 h = *(const short4*)(Bh_ + off);
            short4 l = *(const short4*)(Bl_ + off);
            Bs[c4 + 0][r] = bf2f(h.x) + bf2f(l.x);
            Bs[c4 + 1][r] = bf2f(h.y) + bf2f(l.y);
            Bs[c4 + 2][r] = bf2f(h.z) + bf2f(l.z);
            Bs[c4 + 3][r] = bf2f(h.w) + bf2f(l.w);
        }
        __syncthreads();

        #pragma unroll
        for (int kk = 0; kk < 16; ++kk) {
            double a[4], b[4];
            #pragma unroll
            for (int i = 0; i < 4; ++i) a[i] = (double)As[kk][ty + 16 * i];
            #pragma unroll
            for (int j = 0; j < 4; ++j) b[j] = (double)Bs[kk][tx + 16 * j];
            #pragma unroll
            for (int i = 0; i < 4; ++i)
                #pragma unroll
                for (int j = 0; j < 4; ++j)
                    acc[i][j] = fma(a[i], b[j], acc[i][j]);
        }
        __syncthreads();
    }

    #pragma unroll
    for (int i = 0; i < 4; ++i) {
        int rowl = m0 + ty + 16 * i;
        #pragma unroll
        for (int j = 0; j < 4; ++j)
            C[(long long)rowl * 256 + n0 + tx + 16 * j] = (float)acc[i][j];
    }
}

// =====================================================================
// Fused Sinkhorn: one 1024-thread block per batch; S register-resident.
// =====================================================================
__global__ __launch_bounds__(1024, 4) void sk_fused(float* __restrict__ S,
                                                    const int* __restrict__ n1)
{
    __shared__ float pmax[16][256];
    __shared__ float psum[16][256];
    __shared__ float lseS[256];

    const int b = blockIdx.x;
    const int tid = threadIdx.x;
    const int w = tid >> 6, l = tid & 63;
    const int lim = n1[b];
    float* Sb = S + (long long)b * 65536;

    float4 v[16];
    #pragma unroll
    for (int r = 0; r < 16; ++r) {
        int n = w * 16 + r;
        if (n < lim) {
            float4 x = *(const float4*)(Sb + n * 256 + l * 4);
            v[r].x = x.x / SK_TAU; v[r].y = x.y / SK_TAU;
            v[r].z = x.z / SK_TAU; v[r].w = x.w / SK_TAU;
        } else {
            v[r] = (float4){NEGV, NEGV, NEGV, NEGV};
        }
    }

    for (int it = 0; it < 10; ++it) {
        if ((it & 1) == 0) {
            #pragma unroll
            for (int r = 0; r < 16; ++r) {
                if (w * 16 + r >= lim) continue;
                float m = fmaxf(fmaxf(v[r].x, v[r].y), fmaxf(v[r].z, v[r].w));
                #pragma unroll
                for (int off = 1; off < 64; off <<= 1) m = fmaxf(m, __shfl_xor(m, off));
                float s = expf(v[r].x - m) + expf(v[r].y - m) +
                          expf(v[r].z - m) + expf(v[r].w - m);
                #pragma unroll
                for (int off = 1; off < 64; off <<= 1) s += __shfl_xor(s, off);
                float lse = m + logf(s);
                v[r].x -= lse; v[r].y -= lse; v[r].z -= lse; v[r].w -= lse;
            }
        } else {
            float cm[4] = {-3.4e38f, -3.4e38f, -3.4e38f, -3.4e38f};
            #pragma unroll
            for (int r = 0; r < 16; ++r) {
                cm[0] = fmaxf(cm[0], v[r].x); cm[1] = fmaxf(cm[1], v[r].y);
                cm[2] = fmaxf(cm[2], v[r].z); cm[3] = fmaxf(cm[3], v[r].w);
            }
            float cs[4] = {0.f, 0.f, 0.f, 0.f};
            #pragma unroll
            for (int r = 0; r < 16; ++r) {
                cs[0] += expf(v[r].x - cm[0]); cs[1] += expf(v[r].y - cm[1]);
                cs[2] += expf(v[r].z - cm[2]); cs[3] += expf(v[r].w - cm[3]);
            }
            #pragma unroll
            for (int j = 0; j < 4; ++j) {
                pmax[w][l * 4 + j] = cm[j];
                psum[w][l * 4 + j] = cs[j];
            }
            __syncthreads();
            if (tid < 256) {
                float m = -3.4e38f, s = 0.f;
                #pragma unroll
                for (int ww = 0; ww < 16; ++ww) {
                    float pm = pmax[ww][tid], ps = psum[ww][tid];
                    float nm = fmaxf(m, pm);
                    s = s * expf(m - nm) + ps * expf(pm - nm);
                    m = nm;
                }
                lseS[tid] = m + logf(s);
            }
            __syncthreads();
            float l0 = lseS[l * 4 + 0], l1 = lseS[l * 4 + 1];
            float l2 = lseS[l * 4 + 2], l3 = lseS[l * 4 + 3];
            #pragma unroll
            for (int r = 0; r < 16; ++r) {
                if (w * 16 + r >= lim) continue;
                v[r].x -= l0; v[r].y -= l1; v[r].z -= l2; v[r].w -= l3;
            }
        }
    }

    #pragma unroll
    for (int r = 0; r < 16; ++r) {
        int n = w * 16 + r;
        float4 o;
        if (n < lim) {
            o.x = expf(v[r].x); o.y = expf(v[r].y);
            o.z = expf(v[r].z); o.w = expf(v[r].w);
        } else {
            o = (float4){0.f, 0.f, 0.f, 0.f};
        }
        *(float4*)(Sb + n * 256 + l * 4) = o;
    }
}

// ---------------- launch wrappers ----------------
static void set_lds_attr() {
    static bool done = false;
    if (done) return;
    hipFuncSetAttribute((const void*)gemm_w8<0>,
                        hipFuncAttributeMaxDynamicSharedMemorySize, 131072);
    hipFuncSetAttribute((const void*)gemm_w8<1>,
                        hipFuncAttributeMaxDynamicSharedMemorySize, 131072);
    done = true;
}

static void gw(hipStream_t st, int om, const short* Ah, const short* Al, int lda,
               const float* Bf, int K,
               float* Cf, short* Ch, short* Cl, const float* bias, int relu)
{
    set_lds_attr();
    dim3 grid(8, 32), block(512);
    if (om == 0)
        gemm_w8<0><<<grid, block, 131072, st>>>(Ah, Al, Ah, Al, K, lda, Bf, K,
                                                Cf, nullptr, nullptr, bias, relu);
    else
        gemm_w8<1><<<grid, block, 131072, st>>>(Ah, Al, Ah, Al, K, lda, Bf, K,
                                                nullptr, Ch, Cl, bias, relu);
}

static void gwcat(hipStream_t st, const short* A1h, const short* A1l,
                  const short* A2h, const short* A2l,
                  const float* Bf, short* Ch, short* Cl, const float* bias)
{
    set_lds_attr();
    dim3 grid(8, 32), block(512);
    gemm_w8<1><<<grid, block, 131072, st>>>(A1h, A1l, A2h, A2l, 2048, 2048, Bf, 4096,
                                            nullptr, Ch, Cl, bias, 0);
}

// ---------------- driver ----------------
extern "C" void kernel_launch(void* const* d_in, const int* in_sizes, int n_in,
                              void* d_out, int out_size, void* d_ws, size_t ws_size,
                              hipStream_t stream)
{
    const float* feat1 = (const float*)d_in[0];
    const float* feat2 = (const float*)d_in[1];
    const float* A1    = (const float*)d_in[2];
    const float* A2    = (const float*)d_in[3];
    const int*   n1    = (const int*)d_in[4];
    const float* W0a = (const float*)d_in[8];  const float* b0a = (const float*)d_in[9];
    const float* W0u = (const float*)d_in[10]; const float* b0u = (const float*)d_in[11];
    const float* W1a = (const float*)d_in[12]; const float* b1a = (const float*)d_in[13];
    const float* W1u = (const float*)d_in[14]; const float* b1u = (const float*)d_in[15];
    const float* Wc  = (const float*)d_in[16]; const float* bc  = (const float*)d_in[17];
    const float* Aaff0 = (const float*)d_in[18];
    const float* Aaff1 = (const float*)d_in[19];

    const long long TSZ = 16777216LL;
    const long long PL  = 16777216LL;
    const long long PF  = 8388608LL;

    float* T1f = (float*)d_ws;
    float* T2f = T1f + TSZ;
    float* T3f = T2f + TSZ;
    float* T4f = T3f + TSZ;
    short *T1h = (short*)T1f, *T1l = T1h + PL;
    short *T2h = (short*)T2f, *T2l = T2h + PL;
    short *T3h = (short*)T3f, *T3l = T3h + PL;
    short *T4h = (short*)T4f, *T4l = T4h + PL;

    short* f1h = (short*)T4f;      short* f1l = f1h + PF;
    short* f2h = f1h + 2 * PF;     short* f2l = f1h + 3 * PF;
    float* invA = (float*)T4f;     // overlaps f1h rows: written only after
    float* invB = invA + 8192;     // the last f1 read (ordering below)

    float* S    = (float*)d_out;
    float* inv1 = S;
    float* inv2 = S + 8192;

    dim3 bgrid(16, 2, 32), bblk(256);

    // ===== Phase 0: split feats =====
    split_mat<<<2048, 256, 0, stream>>>(feat1, f1h, f1l, 8192LL * 1024 / 4);
    split_mat<<<2048, 256, 0, stream>>>(feat2, f2h, f2l, 8192LL * 1024 / 4);

    // ===== Phase 1: gconv layer 0 (K=1024, lda=1024) =====
    gw(stream, 1, f1h, f1l, 1024, W0u, 1024, nullptr, T1h, T1l, b0u, 1);
    gw(stream, 1, f2h, f2l, 1024, W0u, 1024, nullptr, T2h, T2l, b0u, 1);
    gw(stream, 1, f1h, f1l, 1024, W0a, 1024, nullptr, T3h, T3l, b0a, 1);   // last f1 read
    colnorm_k<<<32, 256, 0, stream>>>(A1, invA);
    colnorm_k<<<32, 256, 0, stream>>>(A2, invB);
    bgemm_m<false, true><<<bgrid, bblk, 0, stream>>>(A1, T3h, T3l, T1h, T1l, invA);
    gw(stream, 1, f2h, f2l, 1024, W0a, 1024, nullptr, T3h, T3l, b0a, 1);
    bgemm_m<false, true><<<bgrid, bblk, 0, stream>>>(A2, T3h, T3l, T2h, T2l, invB);

    // ===== Phase 2: affinity 0 =====
    gw(stream, 0, T1h, T1l, 2048, Aaff0, 2048, T3f, nullptr, nullptr, nullptr, 0);
    gemm_bt_f64<<<dim3(4, 4, 32), 256, 0, stream>>>(T3f, T2h, T2l, S);

    sk_fused<<<32, 1024, 0, stream>>>(S, n1);

    // ===== Phase 4: cross-graph update =====
    bgemm_m<false, false><<<bgrid, bblk, 0, stream>>>(S, T2h, T2l, T3h, T3l, nullptr); // c1 = S @ emb2
    gwcat(stream, T1h, T1l, T3h, T3l, Wc, T4h, T4l, bc);   // new1 = [emb1|c1]@Wc+bc
    bgemm_m<true, false><<<bgrid, bblk, 0, stream>>>(S, T1h, T1l, T3h, T3l, nullptr);  // c2 = S^T @ emb1
    gwcat(stream, T2h, T2l, T3h, T3l, Wc, T1h, T1l, bc);   // new2 = [emb2|c2]@Wc+bc

    // ===== Phase 5: gconv layer 1 (K=2048, lda=2048) =====
    gw(stream, 1, T4h, T4l, 2048, W1a, 2048, nullptr, T2h, T2l, b1a, 1);   // a-path g1
    gw(stream, 1, T4h, T4l, 2048, W1u, 2048, nullptr, T3h, T3l, b1u, 1);   // u-path g1
    colnorm_k<<<32, 256, 0, stream>>>(A1, inv1);
    bgemm_m<false, true><<<bgrid, bblk, 0, stream>>>(A1, T2h, T2l, T3h, T3l, inv1);    // emb1' = T3
    gw(stream, 1, T1h, T1l, 2048, W1a, 2048, nullptr, T2h, T2l, b1a, 1);   // a-path g2
    gw(stream, 1, T1h, T1l, 2048, W1u, 2048, nullptr, T4h, T4l, b1u, 1);   // u-path g2
    colnorm_k<<<32, 256, 0, stream>>>(A2, inv2);
    bgemm_m<false, true><<<bgrid, bblk, 0, stream>>>(A2, T2h, T2l, T4h, T4l, inv2);    // emb2' = T4

    // ===== Phase 6: affinity 1 =====
    gw(stream, 0, T3h, T3l, 2048, Aaff1, 2048, T1f, nullptr, nullptr, nullptr, 0);
    gemm_bt_f64<<<dim3(4, 4, 32), 256, 0, stream>>>(T1f, T4h, T4l, S);

    sk_fused<<<32, 1024, 0, stream>>>(S, n1);
}